// Round 8
// baseline (781.448 us; speedup 1.0000x reference)
//
#include <hip/hip_runtime.h>
#include <hip/hip_bf16.h>

// Problem constants (fixed by setup_inputs)
#define NN 8192
#define FF 512
#define HH 256
#define RR 16
#define BB 32
#define LL 256
#define CC 7
#define EE 262144
#define NBASE 30
#define DD 768

constexpr int FLAG_BIAS = 1, FLAG_ACC = 2, FLAG_RELU = 4, FLAG_TANH = 8, FLAG_SPLITOUT = 16;

typedef __attribute__((ext_vector_type(8))) short bf16x8;
typedef __attribute__((ext_vector_type(4))) float f32x4;

// ------------- dtype detection (robustness) -----------------------------------
__global__ __launch_bounds__(256) void detect_dtype(const unsigned short* __restrict__ xs,
                                                    int* __restrict__ flag) {
  __shared__ int red[256];
  int cnt = 0;
  for (int i = threadIdx.x * 2; i < 8192; i += 512) {
    unsigned short u = xs[i];
    int e = (u >> 7) & 0xFF;
    if (e >= 0xC0) cnt++;
  }
  red[threadIdx.x] = cnt;
  __syncthreads();
  for (int s = 128; s > 0; s >>= 1) {
    if (threadIdx.x < s) red[threadIdx.x] += red[threadIdx.x + s];
    __syncthreads();
  }
  if (threadIdx.x == 0) flag[0] = (red[0] > 16) ? 1 : 0;  // 1 = fp32 data
}

__global__ __launch_bounds__(256) void conv_f32(const void* __restrict__ src,
                                                float* __restrict__ dst, int n,
                                                const int* __restrict__ flag) {
  const int fp32 = flag[0];
  for (int i = blockIdx.x * 256 + threadIdx.x; i < n; i += gridDim.x * 256)
    dst[i] = fp32 ? ((const float*)src)[i]
                  : __bfloat162float(((const __hip_bfloat16*)src)[i]);
}

// transpose + hi/lo split: src [R][C] -> hi/lo [C][R]
__global__ __launch_bounds__(256) void split_t_b16(const void* __restrict__ src,
                                                   __hip_bfloat16* __restrict__ hi,
                                                   __hip_bfloat16* __restrict__ lo,
                                                   int R, int C, const int* __restrict__ flag) {
  const int fp32 = flag[0];
  int total = R * C;
  for (int idx = blockIdx.x * 256 + threadIdx.x; idx < total; idx += gridDim.x * 256) {
    int r = idx % R, c = idx / R;
    float v = fp32 ? ((const float*)src)[(long)r * C + c]
                   : __bfloat162float(((const __hip_bfloat16*)src)[(long)r * C + c]);
    __hip_bfloat16 h = __float2bfloat16(v);
    hi[idx] = h;
    lo[idx] = __float2bfloat16(v - __bfloat162float(h));
  }
}

// hi/lo split, no transpose
__global__ __launch_bounds__(256) void split_f32(const float* __restrict__ src,
                                                 __hip_bfloat16* __restrict__ hi,
                                                 __hip_bfloat16* __restrict__ lo, int n) {
  for (int i = blockIdx.x * 256 + threadIdx.x; i < n; i += gridDim.x * 256) {
    float v = src[i];
    __hip_bfloat16 h = __float2bfloat16(v);
    hi[i] = h;
    lo[i] = __float2bfloat16(v - __bfloat162float(h));
  }
}

// batched bf16 transpose: src [z][S][D] -> dst [z][D][S]  (S=256, D=768)
__global__ __launch_bounds__(256) void transpose_b16(
    const __hip_bfloat16* __restrict__ src, __hip_bfloat16* __restrict__ dst) {
  __shared__ __hip_bfloat16 t[32][33];
  const long b = blockIdx.z;
  const int d0 = blockIdx.x * 32, s0 = blockIdx.y * 32;
  const int c = threadIdx.x & 31, rw = threadIdx.x >> 5;
  const __hip_bfloat16* sp = src + b * (LL * DD);
  __hip_bfloat16* dp = dst + b * (LL * DD);
#pragma unroll
  for (int i = 0; i < 4; ++i)
    t[rw + i * 8][c] = sp[(long)(s0 + rw + i * 8) * DD + d0 + c];
  __syncthreads();
#pragma unroll
  for (int i = 0; i < 4; ++i)
    dp[(long)(d0 + rw + i * 8) * LL + s0 + c] = t[c][rw + i * 8];
}

// ---- wt_nat[r][f][h] = sum_b comp[r,b]*basis[b][f][h] ------------------------
__global__ __launch_bounds__(256) void wt_gemm(
    const float* __restrict__ basis, const float* __restrict__ comp,
    float* __restrict__ wt_nat) {
  __shared__ float cs[RR * NBASE];
  int tid = threadIdx.x;
  for (int i = tid; i < RR * NBASE; i += 256) cs[i] = comp[i];
  __syncthreads();
  long col = (long)blockIdx.x * 256 + tid;  // 0..131071 (f*256+h)
  float acc[RR] = {};
  for (int b = 0; b < NBASE; ++b) {
    float v = basis[(long)b * 131072 + col];
#pragma unroll
    for (int r = 0; r < RR; ++r) acc[r] += cs[r * NBASE + b] * v;
  }
#pragma unroll
  for (int r = 0; r < RR; ++r) wt_nat[(long)r * 131072 + col] = acc[r];
}

// ---- wt_nat [16][512][256] (r,f,h) -> Wt_t[(r*256+h)][512] hi/lo -------------
__global__ __launch_bounds__(256) void wt_transpose(
    const float* __restrict__ wt_nat,
    __hip_bfloat16* __restrict__ hi, __hip_bfloat16* __restrict__ lo) {
  __shared__ float t[32][33];
  const int r = blockIdx.z;
  const int f0 = blockIdx.y * 32, h0 = blockIdx.x * 32;
  const int c = threadIdx.x & 31, rw = threadIdx.x >> 5;
  const float* src = wt_nat + ((long)r * 512 + f0) * 256 + h0;
#pragma unroll
  for (int i = 0; i < 4; ++i)
    t[rw + i * 8][c] = src[(long)(rw + i * 8) * 256 + c];
  __syncthreads();
#pragma unroll
  for (int i = 0; i < 4; ++i) {
    int hh = rw + i * 8;
    float v = t[c][hh];
    long orow = (long)(r * 256 + h0 + hh) * 512 + f0 + c;
    __hip_bfloat16 hv = __float2bfloat16(v);
    hi[orow] = hv;
    lo[orow] = __float2bfloat16(v - __bfloat162float(hv));
  }
}

// ---------------- split-precision MFMA GEMM (batched, swizzled LDS) -----------
// C[M,N] = (Ahi+Alo)@(Bthi+Btlo)^T minus lo*lo term; 128x128 tile, BK=32,
// 4 waves (2x2 of 64x64), 16x16x32 bf16 MFMA, global_load_lds width=16.
// LDS layout XOR-swizzled (physical chunk c of row R holds global chunk
// c ^ ((R + R>>2)&3)) so ds_read_b128 beats touch all 32 banks.
__device__ __forceinline__ void gload_lds16(const void* g, void* l) {
  __builtin_amdgcn_global_load_lds(
      (const __attribute__((address_space(1))) unsigned int*)g,
      (__attribute__((address_space(3))) unsigned int*)l, 16, 0, 0);
}

__global__ __launch_bounds__(256) void mfma_gemm3(
    const __hip_bfloat16* __restrict__ A, const __hip_bfloat16* __restrict__ Alo,
    const __hip_bfloat16* __restrict__ Bt, const __hip_bfloat16* __restrict__ Btlo,
    const float* __restrict__ bias, float* __restrict__ C,
    __hip_bfloat16* __restrict__ Chi, __hip_bfloat16* __restrict__ Clo,
    int K, int ldc, long sA, long sB, long sC, int flags) {
  __shared__ __hip_bfloat16 As[128 * 32];
  __shared__ __hip_bfloat16 Bs[128 * 32];
  const int tid = threadIdx.x;
  const int w = tid >> 6, lane = tid & 63;
  const long z = blockIdx.z;
  const long row0 = (long)blockIdx.y * 128, col0 = (long)blockIdx.x * 128;
  const int wm = w & 1, wn = w >> 1;
  const int srow0 = (w * 128 + lane) >> 2;
  const int srow1 = (w * 128 + 64 + lane) >> 2;
  const int ch = lane & 3;
  const int pc0 = (ch ^ ((srow0 + (srow0 >> 2)) & 3)) * 8;
  const int pc1 = (ch ^ ((srow1 + (srow1 >> 2)) & 3)) * 8;
  const int fr = lane & 15, q = lane >> 4;
  const int sw = (fr + (fr >> 2)) & 3;
  const int qs = (q ^ sw) * 8;
  f32x4 acc[4][4] = {};
  for (int sweep = 0; sweep < 3; ++sweep) {
    const __hip_bfloat16* Ac = (sweep == 2) ? Alo : A;
    const __hip_bfloat16* Bc = (sweep == 1) ? Btlo : Bt;
    if (Ac == nullptr || Bc == nullptr) continue;
    Ac += z * sA;
    Bc += z * sB;
    const __hip_bfloat16* pa0 = Ac + (row0 + srow0) * K + pc0;
    const __hip_bfloat16* pa1 = Ac + (row0 + srow1) * K + pc1;
    const __hip_bfloat16* pb0 = Bc + (col0 + srow0) * K + pc0;
    const __hip_bfloat16* pb1 = Bc + (col0 + srow1) * K + pc1;
    for (int k0 = 0; k0 < K; k0 += 32) {
      gload_lds16(pa0 + k0, As + w * 1024);
      gload_lds16(pa1 + k0, As + w * 1024 + 512);
      gload_lds16(pb0 + k0, Bs + w * 1024);
      gload_lds16(pb1 + k0, Bs + w * 1024 + 512);
      __syncthreads();
      bf16x8 af[4], bfr[4];
#pragma unroll
      for (int i = 0; i < 4; ++i) {
        af[i] = *(const bf16x8*)&As[(wm * 64 + i * 16 + fr) * 32 + qs];
        bfr[i] = *(const bf16x8*)&Bs[(wn * 64 + i * 16 + fr) * 32 + qs];
      }
#pragma unroll
      for (int i = 0; i < 4; ++i)
#pragma unroll
        for (int j = 0; j < 4; ++j)
          acc[i][j] = __builtin_amdgcn_mfma_f32_16x16x32_bf16(af[i], bfr[j], acc[i][j], 0, 0, 0);
      __syncthreads();
    }
  }
  const int cr = (lane >> 4) * 4, cc = lane & 15;
  float* Cz = C + z * sC;
  __hip_bfloat16* Chz = Chi + z * sC;
  __hip_bfloat16* Clz = Clo + z * sC;
#pragma unroll
  for (int i = 0; i < 4; ++i) {
    long rbase = row0 + wm * 64 + i * 16 + cr;
#pragma unroll
    for (int j = 0; j < 4; ++j) {
      long col = col0 + wn * 64 + j * 16 + cc;
      float bv = (flags & FLAG_BIAS) ? bias[col] : 0.f;
#pragma unroll
      for (int r = 0; r < 4; ++r) {
        float v = acc[i][j][r] + bv;
        if (flags & FLAG_RELU) v = fmaxf(v, 0.f);
        if (flags & FLAG_TANH) v = tanhf(v);
        long off = (rbase + r) * ldc + col;
        if (flags & FLAG_SPLITOUT) {
          __hip_bfloat16 hv = __float2bfloat16(v);
          Chz[off] = hv;
          Clz[off] = __float2bfloat16(v - __bfloat162float(hv));
        } else {
          Cz[off] = v;
        }
      }
    }
  }
}

// ---------------- fp32 64x64 tiled GEMM (out2 chain) --------------------------
__global__ __launch_bounds__(256) void gemm_nn(
    const float* __restrict__ A, const float* __restrict__ B,
    const float* __restrict__ bias, float* __restrict__ C,
    int M, int N, int K, int lda, int ldb, int ldc,
    long sA, long sB, long sC, int flags) {
  const int bz = blockIdx.z;
  A += (long)bz * sA; B += (long)bz * sB; C += (long)bz * sC;
  __shared__ float As[16][68];
  __shared__ float Bs[16][68];
  const int tid = threadIdx.x;
  const int tx = tid & 15, ty = tid >> 4;
  const int row0 = blockIdx.y * 64, col0 = blockIdx.x * 64;
  const int am = tid >> 2, ak = (tid & 3) * 4;
  const int bk = tid >> 4, bn = (tid & 15) * 4;
  float acc[4][4] = {};
  for (int k0 = 0; k0 < K; k0 += 16) {
    const float* Ap = A + (long)(row0 + am) * lda + k0 + ak;
#pragma unroll
    for (int j = 0; j < 4; ++j) As[ak + j][am] = Ap[j];
    const float* Bp = B + (long)(k0 + bk) * ldb + col0 + bn;
#pragma unroll
    for (int j = 0; j < 4; ++j) Bs[bk][bn + j] = Bp[j];
    __syncthreads();
#pragma unroll
    for (int kk = 0; kk < 16; ++kk) {
      float4 av = *(const float4*)&As[kk][ty * 4];
      float4 bv = *(const float4*)&Bs[kk][tx * 4];
      float a[4] = {av.x, av.y, av.z, av.w};
      float b[4] = {bv.x, bv.y, bv.z, bv.w};
#pragma unroll
      for (int i = 0; i < 4; ++i)
#pragma unroll
        for (int j = 0; j < 4; ++j) acc[i][j] += a[i] * b[j];
    }
    __syncthreads();
  }
#pragma unroll
  for (int i = 0; i < 4; ++i) {
    int r = row0 + ty * 4 + i;
#pragma unroll
    for (int j = 0; j < 4; ++j) {
      int c = col0 + tx * 4 + j;
      float v = acc[i][j];
      if (flags & FLAG_BIAS) v += bias[c];
      float* p = C + (long)r * ldc + c;
      if (flags & FLAG_ACC) v += *p;
      if (flags & FLAG_RELU) v = fmaxf(v, 0.f);
      *p = v;
    }
  }
}

// ---------------- edge kernels: CSR build + gathers ----------------------------
__global__ __launch_bounds__(256) void count_edges(
    const int* __restrict__ ei, const int* __restrict__ et, float* __restrict__ cnt) {
  int e = blockIdx.x * 256 + threadIdx.x;
  if (e < EE) atomicAdd(&cnt[ei[EE + e] * RR + et[e]], 1.0f);
}

__global__ __launch_bounds__(256) void scan_rowptr(
    const float* __restrict__ cntf, int* __restrict__ rowptr, int* __restrict__ fill) {
  __shared__ int part[256];
  int tid = threadIdx.x;
  int base = tid * 32;
  int local[32];
  int s = 0;
  for (int i = 0; i < 32; ++i) {
    local[i] = s;
    const float* c = &cntf[(base + i) * RR];
    int d = 0;
#pragma unroll
    for (int r = 0; r < RR; ++r) d += (int)c[r];
    s += d;
  }
  part[tid] = s;
  __syncthreads();
  for (int off = 1; off < 256; off <<= 1) {
    int v = (tid >= off) ? part[tid - off] : 0;
    __syncthreads();
    part[tid] += v;
    __syncthreads();
  }
  int prev = (tid == 0) ? 0 : part[tid - 1];
  for (int i = 0; i < 32; ++i) rowptr[base + i] = prev + local[i];
  if (tid == 255) rowptr[8192] = part[255];
  for (int i = tid; i < 8192; i += 256) fill[i] = 0;
}

__global__ __launch_bounds__(256) void edge_fill(
    const int* __restrict__ ei, const int* __restrict__ et,
    const int* __restrict__ rowptr, int* __restrict__ fill, int* __restrict__ eidx) {
  int e = blockIdx.x * 256 + threadIdx.x;
  if (e < EE) {
    int dst = ei[EE + e];
    int pos = rowptr[dst] + atomicAdd(&fill[dst], 1);
    eidx[pos] = ei[e] | (et[e] << 16);
  }
}

__global__ __launch_bounds__(256) void rgcn_gather(
    const int* __restrict__ rowptr, const int* __restrict__ eidx,
    const float* __restrict__ cntf, const float* __restrict__ xw,
    float* __restrict__ out1) {
  const int dst = blockIdx.x;
  const int h = threadIdx.x;
  __shared__ float inv[RR];
  __shared__ int se[256];
  if (h < RR) inv[h] = 1.0f / fmaxf(cntf[dst * RR + h], 1.0f);
  const int beg = rowptr[dst], end = rowptr[dst + 1];
  float acc = 0.f;
  for (int c0 = beg; c0 < end; c0 += 256) {
    int n = min(256, end - c0);
    __syncthreads();
    if (h < n) se[h] = eidx[c0 + h];
    __syncthreads();
    for (int i = 0; i < n; ++i) {
      int pk = se[i];
      int src = pk & 0xFFFF, r = pk >> 16;
      acc += xw[((long)src << 12) + (r << 8) + h] * inv[r];
    }
  }
  out1[((long)dst << 8) + h] += acc;
}

__global__ __launch_bounds__(256) void graphconv_gather(
    const int* __restrict__ rowptr, const int* __restrict__ eidx,
    const float* __restrict__ out1, float* __restrict__ agg2) {
  const int dst = blockIdx.x;
  const int h = threadIdx.x;
  __shared__ int se[256];
  const int beg = rowptr[dst], end = rowptr[dst + 1];
  float acc = 0.f;
  for (int c0 = beg; c0 < end; c0 += 256) {
    int n = min(256, end - c0);
    __syncthreads();
    if (h < n) se[h] = eidx[c0 + h];
    __syncthreads();
    for (int i = 0; i < n; ++i)
      acc += out1[((long)(se[i] & 0xFFFF) << 8) + h];
  }
  agg2[((long)dst << 8) + h] = acc;
}

// ---------------- copy x (fp32) into emotions[:, 0:512] -----------------------
__global__ __launch_bounds__(256) void copy_x(
    const float* __restrict__ x, float* __restrict__ em) {
  int idx = blockIdx.x * 256 + threadIdx.x;
  int n = idx >> 9, f = idx & 511;
  em[(long)n * DD + f] = x[idx];
}

// ---------------- softmax over last dim (256), bf16 weights out ---------------
__global__ __launch_bounds__(256) void softmax256(const float* __restrict__ S,
                                                  __hip_bfloat16* __restrict__ Ab) {
  __shared__ float red[256];
  long row = blockIdx.x;
  const float* p = S + row * 256;
  int t = threadIdx.x;
  float v = p[t];
  red[t] = v;
  __syncthreads();
  for (int s = 128; s > 0; s >>= 1) {
    if (t < s) red[t] = fmaxf(red[t], red[t + s]);
    __syncthreads();
  }
  float m = red[0];
  __syncthreads();
  float e = __expf(v - m);
  red[t] = e;
  __syncthreads();
  for (int s = 128; s > 0; s >>= 1) {
    if (t < s) red[t] += red[t + s];
    __syncthreads();
  }
  Ab[row * 256 + t] = __float2bfloat16(e / red[0]);
}

// ---------------- logits + log_softmax over batch axis (faithful dim=1) -------
__global__ __launch_bounds__(256) void logits_lsm(
    const float* __restrict__ hidden, const float* __restrict__ w_fc,
    const float* __restrict__ b_fc, void* __restrict__ out_v,
    const int* __restrict__ flag) {
  __shared__ float wf[256 * 7];
  __shared__ float lg[224];
  __shared__ float corr[7];
  int t = blockIdx.x;
  int tid = threadIdx.x;
  for (int i = tid; i < 256 * 7; i += 256) wf[i] = w_fc[i];
  __syncthreads();
  if (tid < 224) {
    int b = tid / 7, c = tid % 7;
    const float* hr = hidden + ((long)((b << 8) + t) << 8);
    float s = b_fc[c];
    for (int k = 0; k < 256; ++k) s += hr[k] * wf[k * 7 + c];
    lg[tid] = s;
  }
  __syncthreads();
  if (tid < 7) {
    float m = -1e30f;
    for (int b = 0; b < BB; ++b) m = fmaxf(m, lg[b * 7 + tid]);
    float sum = 0.f;
    for (int b = 0; b < BB; ++b) sum += __expf(lg[b * 7 + tid] - m);
    corr[tid] = m + logf(sum);
  }
  __syncthreads();
  if (tid < 224) {
    float v = lg[tid] - corr[tid % 7];
    if (flag[0]) ((float*)out_v)[t * 224 + tid] = v;
    else ((__hip_bfloat16*)out_v)[t * 224 + tid] = __float2bfloat16(v);
  }
}

extern "C" void kernel_launch(void* const* d_in, const int* in_sizes, int n_in,
                              void* d_out, int out_size, void* d_ws, size_t ws_size,
                              hipStream_t stream) {
  const int* ei = (const int*)d_in[1];
  const int* et = (const int*)d_in[3];

  float* ws = (float*)d_ws;
  int* flag = (int*)d_ws;
  float* p = ws + 16;
  auto alloc = [&](long nf) { float* r = p; p += nf; return r; };
  float* w_rel_f = alloc(65536);
  float* w_root_f = alloc(65536);
  float* w_fc_f = alloc(1792);
  float* b_rel_f = alloc(256);
  float* bias1_f = alloc(256);
  float* b_att_f = alloc(768);
  float* b_lin_f = alloc(256);
  float* b_fc_f = alloc(16);
  __hip_bfloat16* wlin_hi = (__hip_bfloat16*)alloc(98304);       // [256][768]
  __hip_bfloat16* wlin_lo = (__hip_bfloat16*)alloc(98304);
  float* x_f = alloc(4194304);                                   // [8192][512] fp32
  __hip_bfloat16* x_hi = (__hip_bfloat16*)alloc(2097152);        // [8192][512]
  __hip_bfloat16* x_lo = (__hip_bfloat16*)alloc(2097152);
  __hip_bfloat16* root1_hi = (__hip_bfloat16*)alloc(65536);      // [256][512]
  __hip_bfloat16* root1_lo = (__hip_bfloat16*)alloc(65536);
  __hip_bfloat16* watt_hi = (__hip_bfloat16*)alloc(294912);      // [768][768]
  __hip_bfloat16* watt_lo = (__hip_bfloat16*)alloc(294912);
  __hip_bfloat16* wt_hi = (__hip_bfloat16*)alloc(1048576);       // [4096][512]
  __hip_bfloat16* wt_lo = (__hip_bfloat16*)alloc(1048576);
  float* basis_f = alloc(3932160);
  float* comp_f = alloc(512);
  float* xw = alloc(33554432);   // fp32 [8192][4096]; overlays below
  float* cnt = alloc(131072);
  float* out1 = alloc(2097152);
  float* agg2 = alloc(2097152);
  float* hidden = alloc(2097152);
  int* rowptr = (int*)alloc(8208);
  int* fillc = (int*)alloc(8192);
  int* eidx = (int*)alloc(262144);
  // wt_nat overlays head of xw (consumed by wt_transpose before xw is written)
  float* wt_nat = xw;                                            // [16][512][256]
  // phase B overlays the (consumed) xw region (28.3M of 33.55M floats used)
  float* em = xw;                                                // 6,291,456 f
  __hip_bfloat16* em_hi = (__hip_bfloat16*)(em + 6291456);       // 3,145,728 f
  __hip_bfloat16* em_lo = (__hip_bfloat16*)(em + 9437184);       // 3,145,728 f
  __hip_bfloat16* X_hi = (__hip_bfloat16*)(em + 12582912);       // 3,145,728 f
  __hip_bfloat16* X_lo = (__hip_bfloat16*)(em + 15728640);       // 3,145,728 f
  float* scores = em + 18874368;                                 // 2,097,152 f
  __hip_bfloat16* a_b16 = (__hip_bfloat16*)(em + 20971520);      // 1,048,576 f
  __hip_bfloat16* att_hi = (__hip_bfloat16*)(em + 22020096);     // 3,145,728 f
  __hip_bfloat16* att_lo = (__hip_bfloat16*)(em + 25165824);     // 3,145,728 f
  // emT overlays em fp32 (dead after split_f32(em))
  __hip_bfloat16* emT_hi = (__hip_bfloat16*)em;                  // 3,145,728 f
  __hip_bfloat16* emT_lo = (__hip_bfloat16*)(em + 3145728);      // 3,145,728 f

  // 0. dtype detect + conversions
  detect_dtype<<<1, 256, 0, stream>>>((const unsigned short*)d_in[0], flag);
  auto cvf = [&](int i, float* dst, int n) {
    int grid = (n + 255) / 256; if (grid > 2048) grid = 2048;
    conv_f32<<<grid, 256, 0, stream>>>(d_in[i], dst, n, flag);
  };
  cvf(0, x_f, NN * FF);
  cvf(8, basis_f, NBASE * FF * HH);
  cvf(9, comp_f, RR * NBASE);
  cvf(11, bias1_f, HH);
  cvf(12, w_rel_f, HH * HH);
  cvf(13, b_rel_f, HH);
  cvf(14, w_root_f, HH * HH);
  cvf(16, b_att_f, DD);
  cvf(18, b_lin_f, HH);
  cvf(19, w_fc_f, HH * CC);
  cvf(20, b_fc_f, CC);
  split_f32<<<2048, 256, 0, stream>>>(x_f, x_hi, x_lo, NN * FF);
  split_t_b16<<<512, 256, 0, stream>>>(d_in[10], root1_hi, root1_lo, FF, HH, flag);
  split_t_b16<<<2048, 256, 0, stream>>>(d_in[15], watt_hi, watt_lo, DD, DD, flag);
  split_t_b16<<<768, 256, 0, stream>>>(d_in[17], wlin_hi, wlin_lo, DD, HH, flag);

  // 1. Wt: coalesced GEMM into natural layout, then LDS-tiled transpose + split
  wt_gemm<<<131072 / 256, 256, 0, stream>>>(basis_f, comp_f, wt_nat);
  wt_transpose<<<dim3(8, 16, 16), 256, 0, stream>>>(wt_nat, wt_hi, wt_lo);
  // 2. xw = x @ W (3 sweeps, fp32 out) [8192][4096]
  mfma_gemm3<<<dim3(32, 64, 1), 256, 0, stream>>>(
      x_hi, x_lo, wt_hi, wt_lo, nullptr, xw, nullptr, nullptr, FF, 4096, 0, 0, 0, 0);
  // 3. out1 = x @ root1 + bias1
  mfma_gemm3<<<dim3(2, 64, 1), 256, 0, stream>>>(
      x_hi, x_lo, root1_hi, root1_lo, bias1_f, out1, nullptr, nullptr, FF, HH, 0, 0, 0,
      FLAG_BIAS);
  // 4. CSR build
  hipMemsetAsync(cnt, 0, 131072 * sizeof(float), stream);
  count_edges<<<EE / 256, 256, 0, stream>>>(ei, et, cnt);
  scan_rowptr<<<1, 256, 0, stream>>>(cnt, rowptr, fillc);
  edge_fill<<<EE / 256, 256, 0, stream>>>(ei, et, rowptr, fillc, eidx);
  // 5/6. aggregations (gather, no atomics)
  rgcn_gather<<<NN, 256, 0, stream>>>(rowptr, eidx, cnt, xw, out1);
  graphconv_gather<<<NN, 256, 0, stream>>>(rowptr, eidx, out1, agg2);
  // 7. emotions = [x, out2] (fp32) -> split
  copy_x<<<(NN * FF) / 256, 256, 0, stream>>>(x_f, em);
  gemm_nn<<<dim3(HH / 64, NN / 64, 1), 256, 0, stream>>>(
      agg2, w_rel_f, b_rel_f, em + FF, NN, HH, HH, HH, HH, DD, 0, 0, 0, FLAG_BIAS);
  gemm_nn<<<dim3(HH / 64, NN / 64, 1), 256, 0, stream>>>(
      out1, w_root_f, nullptr, em + FF, NN, HH, HH, HH, HH, DD, 0, 0, 0, FLAG_ACC);
  split_f32<<<2048, 256, 0, stream>>>(em, em_hi, em_lo, NN * DD);
  // 7b. emT (for att B-operand); em fp32 dead, overlay its space
  transpose_b16<<<dim3(24, 8, 32), 256, 0, stream>>>(em_hi, emT_hi);
  transpose_b16<<<dim3(24, 8, 32), 256, 0, stream>>>(em_lo, emT_lo);
  // 8. X = emotions @ w_att + b_att -> split out directly
  mfma_gemm3<<<dim3(6, 64, 1), 256, 0, stream>>>(
      em_hi, em_lo, watt_hi, watt_lo, b_att_f, nullptr, X_hi, X_lo, DD, DD, 0, 0, 0,
      FLAG_BIAS | FLAG_SPLITOUT);
  // 9. scores = tanh(X_b . em_b^T) (batched MFMA, 3 sweeps, fp32 out)
  mfma_gemm3<<<dim3(2, 2, BB), 256, 0, stream>>>(
      X_hi, X_lo, em_hi, em_lo, nullptr, scores, nullptr, nullptr, DD, LL,
      (long)LL * DD, (long)LL * DD, (long)LL * LL, FLAG_TANH);
  // 10. softmax over s -> bf16 attention weights
  softmax256<<<BB * LL, 256, 0, stream>>>(scores, a_b16);
  // 11. att_b = a_b @ em_b (batched MFMA, 2 sweeps, split out)
  mfma_gemm3<<<dim3(6, 2, BB), 256, 0, stream>>>(
      a_b16, nullptr, emT_hi, emT_lo, nullptr, nullptr, att_hi, att_lo, LL, DD,
      (long)LL * LL, (long)LL * DD, (long)LL * DD, FLAG_SPLITOUT);
  // 12. hidden = relu(att @ w_lin + b_lin)
  mfma_gemm3<<<dim3(2, 64, 1), 256, 0, stream>>>(
      att_hi, att_lo, wlin_hi, wlin_lo, b_lin_f, hidden, nullptr, nullptr, DD, HH, 0, 0, 0,
      FLAG_BIAS | FLAG_RELU);
  // 13. logits + log_softmax over batch axis
  logits_lsm<<<LL, 256, 0, stream>>>(hidden, w_fc_f, b_fc_f, d_out, flag);
}

// Round 9
// 721.360 us; speedup vs baseline: 1.0833x; 1.0833x over previous
//
#include <hip/hip_runtime.h>
#include <hip/hip_bf16.h>

// Problem constants (fixed by setup_inputs)
#define NN 8192
#define FF 512
#define HH 256
#define RR 16
#define BB 32
#define LL 256
#define CC 7
#define EE 262144
#define NBASE 30
#define DD 768

constexpr int FLAG_BIAS = 1, FLAG_ACC = 2, FLAG_RELU = 4, FLAG_TANH = 8,
              FLAG_SPLITOUT = 16, FLAG_TAILOUT = 32;

typedef __attribute__((ext_vector_type(8))) short bf16x8;
typedef __attribute__((ext_vector_type(4))) float f32x4;

// ------------- dtype detection (robustness) -----------------------------------
__global__ __launch_bounds__(256) void detect_dtype(const unsigned short* __restrict__ xs,
                                                    int* __restrict__ flag) {
  __shared__ int red[256];
  int cnt = 0;
  for (int i = threadIdx.x * 2; i < 8192; i += 512) {
    unsigned short u = xs[i];
    int e = (u >> 7) & 0xFF;
    if (e >= 0xC0) cnt++;
  }
  red[threadIdx.x] = cnt;
  __syncthreads();
  for (int s = 128; s > 0; s >>= 1) {
    if (threadIdx.x < s) red[threadIdx.x] += red[threadIdx.x + s];
    __syncthreads();
  }
  if (threadIdx.x == 0) flag[0] = (red[0] > 16) ? 1 : 0;  // 1 = fp32 data
}

// ------------- fused conversion: all small tensors in one launch ---------------
struct ConvSeg {
  const void* src;
  float* dst;
  __hip_bfloat16* hi;
  __hip_bfloat16* lo;
  int n;
  int zero;
};
struct ConvTable {
  ConvSeg seg[12];
  int count;
  long total;
};

__global__ __launch_bounds__(256) void conv_all(ConvTable t, const int* __restrict__ flag) {
  const int fp32 = flag[0];
  for (long i = (long)blockIdx.x * 256 + threadIdx.x; i < t.total;
       i += (long)gridDim.x * 256) {
    long off = i;
    int s = 0;
    while (off >= t.seg[s].n) { off -= t.seg[s].n; s++; }
    const ConvSeg& sg = t.seg[s];
    float v = 0.f;
    if (!sg.zero)
      v = fp32 ? ((const float*)sg.src)[off]
               : __bfloat162float(((const __hip_bfloat16*)sg.src)[off]);
    if (sg.dst) sg.dst[off] = v;
    if (sg.hi) {
      __hip_bfloat16 h = __float2bfloat16(v);
      sg.hi[off] = h;
      sg.lo[off] = __float2bfloat16(v - __bfloat162float(h));
    }
  }
}

// transpose + hi/lo split: src [R][C] -> hi/lo [C][R]
__global__ __launch_bounds__(256) void split_t_b16(const void* __restrict__ src,
                                                   __hip_bfloat16* __restrict__ hi,
                                                   __hip_bfloat16* __restrict__ lo,
                                                   int R, int C, const int* __restrict__ flag) {
  const int fp32 = flag[0];
  int total = R * C;
  for (int idx = blockIdx.x * 256 + threadIdx.x; idx < total; idx += gridDim.x * 256) {
    int r = idx % R, c = idx / R;
    float v = fp32 ? ((const float*)src)[(long)r * C + c]
                   : __bfloat162float(((const __hip_bfloat16*)src)[(long)r * C + c]);
    __hip_bfloat16 h = __float2bfloat16(v);
    hi[idx] = h;
    lo[idx] = __float2bfloat16(v - __bfloat162float(h));
  }
}

// hi/lo split, no transpose
__global__ __launch_bounds__(256) void split_f32(const float* __restrict__ src,
                                                 __hip_bfloat16* __restrict__ hi,
                                                 __hip_bfloat16* __restrict__ lo, int n) {
  for (int i = blockIdx.x * 256 + threadIdx.x; i < n; i += gridDim.x * 256) {
    float v = src[i];
    __hip_bfloat16 h = __float2bfloat16(v);
    hi[i] = h;
    lo[i] = __float2bfloat16(v - __bfloat162float(h));
  }
}

// batched bf16 transpose: src [z][S][D] -> dst [z][D][S]  (S=256, D=768)
__global__ __launch_bounds__(256) void transpose_b16(
    const __hip_bfloat16* __restrict__ src, __hip_bfloat16* __restrict__ dst) {
  __shared__ __hip_bfloat16 t[32][33];
  const long b = blockIdx.z;
  const int d0 = blockIdx.x * 32, s0 = blockIdx.y * 32;
  const int c = threadIdx.x & 31, rw = threadIdx.x >> 5;
  const __hip_bfloat16* sp = src + b * (LL * DD);
  __hip_bfloat16* dp = dst + b * (LL * DD);
#pragma unroll
  for (int i = 0; i < 4; ++i)
    t[rw + i * 8][c] = sp[(long)(s0 + rw + i * 8) * DD + d0 + c];
  __syncthreads();
#pragma unroll
  for (int i = 0; i < 4; ++i)
    dp[(long)(d0 + rw + i * 8) * LL + s0 + c] = t[c][rw + i * 8];
}

// ---- wt_nat[r][f][h] = sum_b comp[r,b]*basis[b][f][h] ------------------------
__global__ __launch_bounds__(256) void wt_gemm(
    const float* __restrict__ basis, const float* __restrict__ comp,
    float* __restrict__ wt_nat) {
  __shared__ float cs[RR * NBASE];
  int tid = threadIdx.x;
  for (int i = tid; i < RR * NBASE; i += 256) cs[i] = comp[i];
  __syncthreads();
  long col = (long)blockIdx.x * 256 + tid;
  float acc[RR] = {};
  for (int b = 0; b < NBASE; ++b) {
    float v = basis[(long)b * 131072 + col];
#pragma unroll
    for (int r = 0; r < RR; ++r) acc[r] += cs[r * NBASE + b] * v;
  }
#pragma unroll
  for (int r = 0; r < RR; ++r) wt_nat[(long)r * 131072 + col] = acc[r];
}

// ---- wt_nat [16][512][256] (r,f,h) -> wtc[(r*256+h)][512] hi/lo --------------
__global__ __launch_bounds__(256) void wt_transpose(
    const float* __restrict__ wt_nat,
    __hip_bfloat16* __restrict__ hi, __hip_bfloat16* __restrict__ lo) {
  __shared__ float t[32][33];
  const int r = blockIdx.z;
  const int f0 = blockIdx.y * 32, h0 = blockIdx.x * 32;
  const int c = threadIdx.x & 31, rw = threadIdx.x >> 5;
  const float* src = wt_nat + ((long)r * 512 + f0) * 256 + h0;
#pragma unroll
  for (int i = 0; i < 4; ++i)
    t[rw + i * 8][c] = src[(long)(rw + i * 8) * 256 + c];
  __syncthreads();
#pragma unroll
  for (int i = 0; i < 4; ++i) {
    int hh = rw + i * 8;
    float v = t[c][hh];
    long orow = (long)(r * 256 + h0 + hh) * 512 + f0 + c;
    __hip_bfloat16 hv = __float2bfloat16(v);
    hi[orow] = hv;
    lo[orow] = __float2bfloat16(v - __bfloat162float(hv));
  }
}

// ---------------- fused dual-precision MFMA GEMM ------------------------------
// One K-pass: acc += Ahi@Bhi + Ahi@Blo (+ Alo@Bhi). 128x128 tile, BK=32,
// 4 waves, 16x16x32 bf16 MFMA, global_load_lds width=16, 32 KB LDS (4 tiles).
__device__ __forceinline__ void gload_lds16(const void* g, void* l) {
  __builtin_amdgcn_global_load_lds(
      (const __attribute__((address_space(1))) unsigned int*)g,
      (__attribute__((address_space(3))) unsigned int*)l, 16, 0, 0);
}

__global__ __launch_bounds__(256) void mfma_dual(
    const __hip_bfloat16* __restrict__ A, const __hip_bfloat16* __restrict__ Alo,
    const __hip_bfloat16* __restrict__ Bt, const __hip_bfloat16* __restrict__ Btlo,
    const float* __restrict__ bias, float* __restrict__ C, float* __restrict__ Ct,
    __hip_bfloat16* __restrict__ Chi, __hip_bfloat16* __restrict__ Clo,
    int K, int ldc, long sA, long sB, long sC, int flags) {
  __shared__ __hip_bfloat16 Ah[128 * 32];
  __shared__ __hip_bfloat16 Bh[128 * 32];
  __shared__ __hip_bfloat16 Al[128 * 32];
  __shared__ __hip_bfloat16 Bl[128 * 32];
  const int tid = threadIdx.x;
  const int w = tid >> 6, lane = tid & 63;
  const long z = blockIdx.z;
  const long row0 = (long)blockIdx.y * 128, col0 = (long)blockIdx.x * 128;
  const int wm = w & 1, wn = w >> 1;
  const int srow0 = (w * 128 + lane) >> 2;
  const int srow1 = (w * 128 + 64 + lane) >> 2;
  const int kch = (lane & 3) * 8;
  const int fr = lane & 15, q = lane >> 4;
  const bool hasAlo = (Alo != nullptr);
  const __hip_bfloat16* Az = A + z * sA;
  const __hip_bfloat16* Alz = hasAlo ? (Alo + z * sA) : nullptr;
  const __hip_bfloat16* Bz = Bt + z * sB;
  const __hip_bfloat16* Blz = Btlo + z * sB;
  const long aoff0 = (row0 + srow0) * K + kch, aoff1 = (row0 + srow1) * K + kch;
  const long boff0 = (col0 + srow0) * K + kch, boff1 = (col0 + srow1) * K + kch;
  f32x4 acc[4][4] = {};
  for (int k0 = 0; k0 < K; k0 += 32) {
    gload_lds16(Az + aoff0 + k0, Ah + w * 1024);
    gload_lds16(Az + aoff1 + k0, Ah + w * 1024 + 512);
    gload_lds16(Bz + boff0 + k0, Bh + w * 1024);
    gload_lds16(Bz + boff1 + k0, Bh + w * 1024 + 512);
    gload_lds16(Blz + boff0 + k0, Bl + w * 1024);
    gload_lds16(Blz + boff1 + k0, Bl + w * 1024 + 512);
    if (hasAlo) {
      gload_lds16(Alz + aoff0 + k0, Al + w * 1024);
      gload_lds16(Alz + aoff1 + k0, Al + w * 1024 + 512);
    }
    __syncthreads();
    bf16x8 ah[4], bh[4], bl[4];
#pragma unroll
    for (int i = 0; i < 4; ++i) {
      ah[i] = *(const bf16x8*)&Ah[(wm * 64 + i * 16 + fr) * 32 + q * 8];
      bh[i] = *(const bf16x8*)&Bh[(wn * 64 + i * 16 + fr) * 32 + q * 8];
      bl[i] = *(const bf16x8*)&Bl[(wn * 64 + i * 16 + fr) * 32 + q * 8];
    }
#pragma unroll
    for (int i = 0; i < 4; ++i)
#pragma unroll
      for (int j = 0; j < 4; ++j) {
        acc[i][j] = __builtin_amdgcn_mfma_f32_16x16x32_bf16(ah[i], bh[j], acc[i][j], 0, 0, 0);
        acc[i][j] = __builtin_amdgcn_mfma_f32_16x16x32_bf16(ah[i], bl[j], acc[i][j], 0, 0, 0);
      }
    if (hasAlo) {
      bf16x8 al[4];
#pragma unroll
      for (int i = 0; i < 4; ++i)
        al[i] = *(const bf16x8*)&Al[(wm * 64 + i * 16 + fr) * 32 + q * 8];
#pragma unroll
      for (int i = 0; i < 4; ++i)
#pragma unroll
        for (int j = 0; j < 4; ++j)
          acc[i][j] = __builtin_amdgcn_mfma_f32_16x16x32_bf16(al[i], bh[j], acc[i][j], 0, 0, 0);
    }
    __syncthreads();
  }
  const int cr = (lane >> 4) * 4, cc = lane & 15;
  float* Cz = C ? (C + z * sC) : nullptr;
  __hip_bfloat16* Chz = Chi ? (Chi + z * sC) : nullptr;
  __hip_bfloat16* Clz = Clo ? (Clo + z * sC) : nullptr;
#pragma unroll
  for (int i = 0; i < 4; ++i) {
    long rbase = row0 + wm * 64 + i * 16 + cr;
#pragma unroll
    for (int j = 0; j < 4; ++j) {
      long col = col0 + wn * 64 + j * 16 + cc;
      float bv = (flags & FLAG_BIAS) ? bias[col] : 0.f;
#pragma unroll
      for (int r = 0; r < 4; ++r) {
        float v = acc[i][j][r] + bv;
        if (flags & FLAG_RELU) v = fmaxf(v, 0.f);
        if (flags & FLAG_TANH) v = tanhf(v);
        if (flags & FLAG_SPLITOUT) {
          long off = (rbase + r) * ldc + col;
          __hip_bfloat16 hv = __float2bfloat16(v);
          Chz[off] = hv;
          Clz[off] = __float2bfloat16(v - __bfloat162float(hv));
        } else if ((flags & FLAG_TAILOUT) && col >= 4096) {
          Ct[(rbase + r) * 256 + (col - 4096)] = v;
        } else {
          Cz[(rbase + r) * ldc + col] = v;
        }
      }
    }
  }
}

// ---------------- fp32 64x64 tiled GEMM (out2 chain) --------------------------
__global__ __launch_bounds__(256) void gemm_nn(
    const float* __restrict__ A, const float* __restrict__ B,
    const float* __restrict__ bias, float* __restrict__ C,
    int M, int N, int K, int lda, int ldb, int ldc,
    long sA, long sB, long sC, int flags) {
  const int bz = blockIdx.z;
  A += (long)bz * sA; B += (long)bz * sB; C += (long)bz * sC;
  __shared__ float As[16][68];
  __shared__ float Bs[16][68];
  const int tid = threadIdx.x;
  const int tx = tid & 15, ty = tid >> 4;
  const int row0 = blockIdx.y * 64, col0 = blockIdx.x * 64;
  const int am = tid >> 2, ak = (tid & 3) * 4;
  const int bk = tid >> 4, bn = (tid & 15) * 4;
  float acc[4][4] = {};
  for (int k0 = 0; k0 < K; k0 += 16) {
    const float* Ap = A + (long)(row0 + am) * lda + k0 + ak;
#pragma unroll
    for (int j = 0; j < 4; ++j) As[ak + j][am] = Ap[j];
    const float* Bp = B + (long)(k0 + bk) * ldb + col0 + bn;
#pragma unroll
    for (int j = 0; j < 4; ++j) Bs[bk][bn + j] = Bp[j];
    __syncthreads();
#pragma unroll
    for (int kk = 0; kk < 16; ++kk) {
      float4 av = *(const float4*)&As[kk][ty * 4];
      float4 bv = *(const float4*)&Bs[kk][tx * 4];
      float a[4] = {av.x, av.y, av.z, av.w};
      float b[4] = {bv.x, bv.y, bv.z, bv.w};
#pragma unroll
      for (int i = 0; i < 4; ++i)
#pragma unroll
        for (int j = 0; j < 4; ++j) acc[i][j] += a[i] * b[j];
    }
    __syncthreads();
  }
#pragma unroll
  for (int i = 0; i < 4; ++i) {
    int r = row0 + ty * 4 + i;
#pragma unroll
    for (int j = 0; j < 4; ++j) {
      int c = col0 + tx * 4 + j;
      float v = acc[i][j];
      if (flags & FLAG_BIAS) v += bias[c];
      float* p = C + (long)r * ldc + c;
      if (flags & FLAG_ACC) v += *p;
      if (flags & FLAG_RELU) v = fmaxf(v, 0.f);
      *p = v;
    }
  }
}

// ---------------- edge kernels: CSR build + gathers ----------------------------
__global__ __launch_bounds__(256) void count_edges(
    const int* __restrict__ ei, const int* __restrict__ et, float* __restrict__ cnt) {
  int e = blockIdx.x * 256 + threadIdx.x;
  if (e < EE) atomicAdd(&cnt[ei[EE + e] * RR + et[e]], 1.0f);
}

__global__ __launch_bounds__(256) void scan_rowptr(
    const float* __restrict__ cntf, int* __restrict__ rowptr, int* __restrict__ fill) {
  __shared__ int part[256];
  int tid = threadIdx.x;
  int base = tid * 32;
  int local[32];
  int s = 0;
  for (int i = 0; i < 32; ++i) {
    local[i] = s;
    const float* c = &cntf[(base + i) * RR];
    int d = 0;
#pragma unroll
    for (int r = 0; r < RR; ++r) d += (int)c[r];
    s += d;
  }
  part[tid] = s;
  __syncthreads();
  for (int off = 1; off < 256; off <<= 1) {
    int v = (tid >= off) ? part[tid - off] : 0;
    __syncthreads();
    part[tid] += v;
    __syncthreads();
  }
  int prev = (tid == 0) ? 0 : part[tid - 1];
  for (int i = 0; i < 32; ++i) rowptr[base + i] = prev + local[i];
  if (tid == 255) rowptr[8192] = part[255];
  for (int i = tid; i < 8192; i += 256) fill[i] = 0;
}

__global__ __launch_bounds__(256) void edge_fill(
    const int* __restrict__ ei, const int* __restrict__ et,
    const int* __restrict__ rowptr, int* __restrict__ fill, int* __restrict__ eidx) {
  int e = blockIdx.x * 256 + threadIdx.x;
  if (e < EE) {
    int dst = ei[EE + e];
    int pos = rowptr[dst] + atomicAdd(&fill[dst], 1);
    eidx[pos] = ei[e] | (et[e] << 16);
  }
}

__global__ __launch_bounds__(256) void rgcn_gather(
    const int* __restrict__ rowptr, const int* __restrict__ eidx,
    const float* __restrict__ cntf, const float* __restrict__ xw,
    float* __restrict__ out1) {
  const int dst = blockIdx.x;
  const int h = threadIdx.x;
  __shared__ float inv[RR];
  __shared__ int se[256];
  if (h < RR) inv[h] = 1.0f / fmaxf(cntf[dst * RR + h], 1.0f);
  const int beg = rowptr[dst], end = rowptr[dst + 1];
  float acc = 0.f;
  for (int c0 = beg; c0 < end; c0 += 256) {
    int n = min(256, end - c0);
    __syncthreads();
    if (h < n) se[h] = eidx[c0 + h];
    __syncthreads();
    for (int i = 0; i < n; ++i) {
      int pk = se[i];
      int src = pk & 0xFFFF, r = pk >> 16;
      acc += xw[((long)src << 12) + (r << 8) + h] * inv[r];
    }
  }
  out1[((long)dst << 8) + h] += acc;
}

__global__ __launch_bounds__(256) void graphconv_gather(
    const int* __restrict__ rowptr, const int* __restrict__ eidx,
    const float* __restrict__ out1, float* __restrict__ agg2) {
  const int dst = blockIdx.x;
  const int h = threadIdx.x;
  __shared__ int se[256];
  const int beg = rowptr[dst], end = rowptr[dst + 1];
  float acc = 0.f;
  for (int c0 = beg; c0 < end; c0 += 256) {
    int n = min(256, end - c0);
    __syncthreads();
    if (h < n) se[h] = eidx[c0 + h];
    __syncthreads();
    for (int i = 0; i < n; ++i)
      acc += out1[((long)(se[i] & 0xFFFF) << 8) + h];
  }
  agg2[((long)dst << 8) + h] = acc;
}

// ---------------- copy x (fp32) into emotions[:, 0:512] -----------------------
__global__ __launch_bounds__(256) void copy_x(
    const float* __restrict__ x, float* __restrict__ em) {
  int idx = blockIdx.x * 256 + threadIdx.x;
  int n = idx >> 9, f = idx & 511;
  em[(long)n * DD + f] = x[idx];
}

// ---------------- softmax over last dim (256), bf16 weights out ---------------
__global__ __launch_bounds__(256) void softmax256(const float* __restrict__ S,
                                                  __hip_bfloat16* __restrict__ Ab) {
  __shared__ float red[256];
  long row = blockIdx.x;
  const float* p = S + row * 256;
  int t = threadIdx.x;
  float v = p[t];
  red[t] = v;
  __syncthreads();
  for (int s = 128; s > 0; s >>= 1) {
    if (t < s) red[t] = fmaxf(red[t], red[t + s]);
    __syncthreads();
  }
  float m = red[0];
  __syncthreads();
  float e = __expf(v - m);
  red[t] = e;
  __syncthreads();
  for (int s = 128; s > 0; s >>= 1) {
    if (t < s) red[t] += red[t + s];
    __syncthreads();
  }
  Ab[row * 256 + t] = __float2bfloat16(e / red[0]);
}

// ---------------- logits + log_softmax over batch axis (faithful dim=1) -------
__global__ __launch_bounds__(256) void logits_lsm(
    const float* __restrict__ hidden, const float* __restrict__ w_fc,
    const float* __restrict__ b_fc, void* __restrict__ out_v,
    const int* __restrict__ flag) {
  __shared__ float wf[256 * 7];
  __shared__ float lg[224];
  __shared__ float corr[7];
  int t = blockIdx.x;
  int tid = threadIdx.x;
  for (int i = tid; i < 256 * 7; i += 256) wf[i] = w_fc[i];
  __syncthreads();
  if (tid < 224) {
    int b = tid / 7, c = tid % 7;
    const float* hr = hidden + ((long)((b << 8) + t) << 8);
    float s = b_fc[c];
    for (int k = 0; k < 256; ++k) s += hr[k] * wf[k * 7 + c];
    lg[tid] = s;
  }
  __syncthreads();
  if (tid < 7) {
    float m = -1e30f;
    for (int b = 0; b < BB; ++b) m = fmaxf(m, lg[b * 7 + tid]);
    float sum = 0.f;
    for (int b = 0; b < BB; ++b) sum += __expf(lg[b * 7 + tid] - m);
    corr[tid] = m + logf(sum);
  }
  __syncthreads();
  if (tid < 224) {
    float v = lg[tid] - corr[tid % 7];
    if (flag[0]) ((float*)out_v)[t * 224 + tid] = v;
    else ((__hip_bfloat16*)out_v)[t * 224 + tid] = __float2bfloat16(v);
  }
}

extern "C" void kernel_launch(void* const* d_in, const int* in_sizes, int n_in,
                              void* d_out, int out_size, void* d_ws, size_t ws_size,
                              hipStream_t stream) {
  const int* ei = (const int*)d_in[1];
  const int* et = (const int*)d_in[3];

  float* ws = (float*)d_ws;
  int* flag = (int*)d_ws;
  float* p = ws + 16;
  auto alloc = [&](long nf) { float* r = p; p += nf; return r; };
  float* w_rel_f = alloc(65536);
  float* w_root_f = alloc(65536);
  float* w_fc_f = alloc(1792);
  float* b_rel_f = alloc(256);
  float* biasx = alloc(4352);                                    // [0..4095]=0, tail=bias1
  float* b_att_f = alloc(768);
  float* b_lin_f = alloc(256);
  float* b_fc_f = alloc(16);
  __hip_bfloat16* wlin_hi = (__hip_bfloat16*)alloc(98304);       // [256][768]
  __hip_bfloat16* wlin_lo = (__hip_bfloat16*)alloc(98304);
  float* x_f = alloc(4194304);                                   // [8192][512] fp32
  __hip_bfloat16* x_hi = (__hip_bfloat16*)alloc(2097152);        // [8192][512]
  __hip_bfloat16* x_lo = (__hip_bfloat16*)alloc(2097152);
  __hip_bfloat16* watt_hi = (__hip_bfloat16*)alloc(294912);      // [768][768]
  __hip_bfloat16* watt_lo = (__hip_bfloat16*)alloc(294912);
  __hip_bfloat16* wtc_hi = (__hip_bfloat16*)alloc(1114112);      // [4352][512]
  __hip_bfloat16* wtc_lo = (__hip_bfloat16*)alloc(1114112);
  float* basis_f = alloc(3932160);
  float* comp_f = alloc(512);
  float* xw = alloc(33554432);   // fp32 [8192][4096]; overlays below
  float* cnt = alloc(131072);
  float* out1 = alloc(2097152);
  float* agg2 = alloc(2097152);
  float* hidden = alloc(2097152);
  int* rowptr = (int*)alloc(8208);
  int* fillc = (int*)alloc(8192);
  int* eidx = (int*)alloc(262144);
  // wt_nat overlays head of xw (consumed by wt_transpose before xw is written)
  float* wt_nat = xw;                                            // [16][512][256]
  // phase B overlays the (consumed) xw region (28.3M of 33.55M floats used)
  float* em = xw;                                                // 6,291,456 f
  __hip_bfloat16* em_hi = (__hip_bfloat16*)(em + 6291456);       // 3,145,728 f
  __hip_bfloat16* em_lo = (__hip_bfloat16*)(em + 9437184);       // 3,145,728 f
  __hip_bfloat16* X_hi = (__hip_bfloat16*)(em + 12582912);       // 3,145,728 f
  __hip_bfloat16* X_lo = (__hip_bfloat16*)(em + 15728640);       // 3,145,728 f
  float* scores = em + 18874368;                                 // 2,097,152 f
  __hip_bfloat16* a_b16 = (__hip_bfloat16*)(em + 20971520);      // 1,048,576 f
  __hip_bfloat16* att_hi = (__hip_bfloat16*)(em + 22020096);     // 3,145,728 f
  __hip_bfloat16* att_lo = (__hip_bfloat16*)(em + 25165824);     // 3,145,728 f
  // emT overlays em fp32 (dead after split_f32(em))
  __hip_bfloat16* emT_hi = (__hip_bfloat16*)em;                  // 3,145,728 f
  __hip_bfloat16* emT_lo = (__hip_bfloat16*)(em + 3145728);      // 3,145,728 f

  // 0. dtype detect + single fused conversion launch
  detect_dtype<<<1, 256, 0, stream>>>((const unsigned short*)d_in[0], flag);
  ConvTable T{};
  long tot = 0;
  int ns = 0;
  auto seg = [&](const void* s, float* d, __hip_bfloat16* hi, __hip_bfloat16* lo,
                 int n, int z) {
    T.seg[ns].src = s; T.seg[ns].dst = d; T.seg[ns].hi = hi; T.seg[ns].lo = lo;
    T.seg[ns].n = n; T.seg[ns].zero = z; ns++; tot += n;
  };
  seg(d_in[0], x_f, x_hi, x_lo, NN * FF, 0);
  seg(d_in[8], basis_f, nullptr, nullptr, NBASE * FF * HH, 0);
  seg(d_in[9], comp_f, nullptr, nullptr, RR * NBASE, 0);
  seg(d_in[12], w_rel_f, nullptr, nullptr, HH * HH, 0);
  seg(d_in[13], b_rel_f, nullptr, nullptr, HH, 0);
  seg(d_in[14], w_root_f, nullptr, nullptr, HH * HH, 0);
  seg(d_in[16], b_att_f, nullptr, nullptr, DD, 0);
  seg(d_in[18], b_lin_f, nullptr, nullptr, HH, 0);
  seg(d_in[19], w_fc_f, nullptr, nullptr, HH * CC, 0);
  seg(d_in[20], b_fc_f, nullptr, nullptr, CC, 0);
  seg(nullptr, biasx, nullptr, nullptr, 4096, 1);
  seg(d_in[11], biasx + 4096, nullptr, nullptr, HH, 0);
  T.count = ns;
  T.total = tot;
  conv_all<<<4096, 256, 0, stream>>>(T, flag);
  split_t_b16<<<2048, 256, 0, stream>>>(d_in[15], watt_hi, watt_lo, DD, DD, flag);
  split_t_b16<<<768, 256, 0, stream>>>(d_in[17], wlin_hi, wlin_lo, DD, HH, flag);
  split_t_b16<<<512, 256, 0, stream>>>(d_in[10], wtc_hi + 4096 * 512,
                                       wtc_lo + 4096 * 512, FF, HH, flag);

  // 1. Wt: coalesced GEMM into natural layout, then LDS-tiled transpose + split
  wt_gemm<<<131072 / 256, 256, 0, stream>>>(basis_f, comp_f, wt_nat);
  wt_transpose<<<dim3(8, 16, 16), 256, 0, stream>>>(wt_nat, wtc_hi, wtc_lo);
  // 2. merged xw|out1 = x @ [W | root1] + [0 | bias1]  (cols>=4096 -> out1)
  mfma_dual<<<dim3(34, 64, 1), 256, 0, stream>>>(
      x_hi, x_lo, wtc_hi, wtc_lo, biasx, xw, out1, nullptr, nullptr, FF, 4096,
      0, 0, 0, FLAG_BIAS | FLAG_TAILOUT);
  // 3. CSR build
  hipMemsetAsync(cnt, 0, 131072 * sizeof(float), stream);
  count_edges<<<EE / 256, 256, 0, stream>>>(ei, et, cnt);
  scan_rowptr<<<1, 256, 0, stream>>>(cnt, rowptr, fillc);
  edge_fill<<<EE / 256, 256, 0, stream>>>(ei, et, rowptr, fillc, eidx);
  // 4/5. aggregations (gather, no atomics)
  rgcn_gather<<<NN, 256, 0, stream>>>(rowptr, eidx, cnt, xw, out1);
  graphconv_gather<<<NN, 256, 0, stream>>>(rowptr, eidx, out1, agg2);
  // 6. emotions = [x, out2] (fp32) -> split
  copy_x<<<(NN * FF) / 256, 256, 0, stream>>>(x_f, em);
  gemm_nn<<<dim3(HH / 64, NN / 64, 1), 256, 0, stream>>>(
      agg2, w_rel_f, b_rel_f, em + FF, NN, HH, HH, HH, HH, DD, 0, 0, 0, FLAG_BIAS);
  gemm_nn<<<dim3(HH / 64, NN / 64, 1), 256, 0, stream>>>(
      out1, w_root_f, nullptr, em + FF, NN, HH, HH, HH, HH, DD, 0, 0, 0, FLAG_ACC);
  split_f32<<<2048, 256, 0, stream>>>(em, em_hi, em_lo, NN * DD);
  // 6b. emT (for att B-operand); em fp32 dead, overlay its space
  transpose_b16<<<dim3(24, 8, 32), 256, 0, stream>>>(em_hi, emT_hi);
  transpose_b16<<<dim3(24, 8, 32), 256, 0, stream>>>(em_lo, emT_lo);
  // 7. X = emotions @ w_att + b_att -> split out
  mfma_dual<<<dim3(6, 64, 1), 256, 0, stream>>>(
      em_hi, em_lo, watt_hi, watt_lo, b_att_f, nullptr, nullptr, X_hi, X_lo, DD, DD,
      0, 0, 0, FLAG_BIAS | FLAG_SPLITOUT);
  // 8. scores = tanh(X_b . em_b^T) (batched, fp32 out)
  mfma_dual<<<dim3(2, 2, BB), 256, 0, stream>>>(
      X_hi, X_lo, em_hi, em_lo, nullptr, scores, nullptr, nullptr, nullptr, DD, LL,
      (long)LL * DD, (long)LL * DD, (long)LL * LL, FLAG_TANH);
  // 9. softmax over s -> bf16 attention weights
  softmax256<<<BB * LL, 256, 0, stream>>>(scores, a_b16);
  // 10. att_b = a_b @ em_b (batched, split out)
  mfma_dual<<<dim3(6, 2, BB), 256, 0, stream>>>(
      a_b16, nullptr, emT_hi, emT_lo, nullptr, nullptr, nullptr, att_hi, att_lo, LL, DD,
      (long)LL * LL, (long)LL * DD, (long)LL * DD, FLAG_SPLITOUT);
  // 11. hidden = relu(att @ w_lin + b_lin)
  mfma_dual<<<dim3(2, 64, 1), 256, 0, stream>>>(
      att_hi, att_lo, wlin_hi, wlin_lo, b_lin_f, hidden, nullptr, nullptr, nullptr,
      DD, HH, 0, 0, 0, FLAG_BIAS | FLAG_RELU);
  // 12. logits + log_softmax over batch axis
  logits_lsm<<<LL, 256, 0, stream>>>(hidden, w_fc_f, b_fc_f, d_out, flag);
}

// Round 10
// 697.558 us; speedup vs baseline: 1.1203x; 1.0341x over previous
//
#include <hip/hip_runtime.h>
#include <hip/hip_bf16.h>

// Problem constants (fixed by setup_inputs)
#define NN 8192
#define FF 512
#define HH 256
#define RR 16
#define BB 32
#define LL 256
#define CC 7
#define EE 262144
#define NBASE 30
#define DD 768

constexpr int FLAG_BIAS = 1, FLAG_RELU = 4, FLAG_TANH = 8,
              FLAG_SPLITOUT = 16, FLAG_TAILOUT = 32;

typedef __attribute__((ext_vector_type(8))) short bf16x8;
typedef __attribute__((ext_vector_type(4))) float f32x4;

// ------------- dtype detection (robustness) -----------------------------------
__global__ __launch_bounds__(256) void detect_dtype(const unsigned short* __restrict__ xs,
                                                    int* __restrict__ flag) {
  __shared__ int red[256];
  int cnt = 0;
  for (int i = threadIdx.x * 2; i < 8192; i += 512) {
    unsigned short u = xs[i];
    int e = (u >> 7) & 0xFF;
    if (e >= 0xC0) cnt++;
  }
  red[threadIdx.x] = cnt;
  __syncthreads();
  for (int s = 128; s > 0; s >>= 1) {
    if (threadIdx.x < s) red[threadIdx.x] += red[threadIdx.x + s];
    __syncthreads();
  }
  if (threadIdx.x == 0) flag[0] = (red[0] > 16) ? 1 : 0;  // 1 = fp32 data
}

// ------------- fused conversion: all small tensors in one launch ---------------
struct ConvSeg {
  const void* src;
  float* dst;
  __hip_bfloat16* hi;
  __hip_bfloat16* lo;
  int n;
  int zero;
};
struct ConvTable {
  ConvSeg seg[12];
  int count;
  long total;
};

__global__ __launch_bounds__(256) void conv_all(ConvTable t, const int* __restrict__ flag) {
  const int fp32 = flag[0];
  for (long i = (long)blockIdx.x * 256 + threadIdx.x; i < t.total;
       i += (long)gridDim.x * 256) {
    long off = i;
    int s = 0;
    while (off >= t.seg[s].n) { off -= t.seg[s].n; s++; }
    const ConvSeg& sg = t.seg[s];
    float v = 0.f;
    if (!sg.zero)
      v = fp32 ? ((const float*)sg.src)[off]
               : __bfloat162float(((const __hip_bfloat16*)sg.src)[off]);
    if (sg.dst) sg.dst[off] = v;
    if (sg.hi) {
      __hip_bfloat16 h = __float2bfloat16(v);
      sg.hi[off] = h;
      sg.lo[off] = __float2bfloat16(v - __bfloat162float(h));
    }
  }
}

// transpose + hi/lo split: src [R][C] -> dst row c, col off+r, row stride ld
__global__ __launch_bounds__(256) void split_t_b16(const void* __restrict__ src,
                                                   __hip_bfloat16* __restrict__ hi,
                                                   __hip_bfloat16* __restrict__ lo,
                                                   int R, int C, int ld, int off,
                                                   const int* __restrict__ flag) {
  const int fp32 = flag[0];
  int total = R * C;
  for (int idx = blockIdx.x * 256 + threadIdx.x; idx < total; idx += gridDim.x * 256) {
    int r = idx % R, c = idx / R;
    float v = fp32 ? ((const float*)src)[(long)r * C + c]
                   : __bfloat162float(((const __hip_bfloat16*)src)[(long)r * C + c]);
    __hip_bfloat16 h = __float2bfloat16(v);
    long d = (long)c * ld + off + r;
    hi[d] = h;
    lo[d] = __float2bfloat16(v - __bfloat162float(h));
  }
}

// copy x_hi/x_lo [8192][512] into em_hi/lo [8192][768] cols 0:512
__global__ __launch_bounds__(256) void copy_xsplit(
    const __hip_bfloat16* __restrict__ xh, const __hip_bfloat16* __restrict__ xl,
    __hip_bfloat16* __restrict__ eh, __hip_bfloat16* __restrict__ el) {
  int idx = blockIdx.x * 256 + threadIdx.x;  // 8192*512
  int n = idx >> 9, f = idx & 511;
  long d = (long)n * DD + f;
  eh[d] = xh[idx];
  el[d] = xl[idx];
}

// batched bf16 transpose: src [z][S][D] -> dst [z][D][S]  (S=256, D=768)
__global__ __launch_bounds__(256) void transpose_b16(
    const __hip_bfloat16* __restrict__ src, __hip_bfloat16* __restrict__ dst) {
  __shared__ __hip_bfloat16 t[32][33];
  const long b = blockIdx.z;
  const int d0 = blockIdx.x * 32, s0 = blockIdx.y * 32;
  const int c = threadIdx.x & 31, rw = threadIdx.x >> 5;
  const __hip_bfloat16* sp = src + b * (LL * DD);
  __hip_bfloat16* dp = dst + b * (LL * DD);
#pragma unroll
  for (int i = 0; i < 4; ++i)
    t[rw + i * 8][c] = sp[(long)(s0 + rw + i * 8) * DD + d0 + c];
  __syncthreads();
#pragma unroll
  for (int i = 0; i < 4; ++i)
    dp[(long)(d0 + rw + i * 8) * LL + s0 + c] = t[c][rw + i * 8];
}

// ---- wt_nat[r][f][h] = sum_b comp[r,b]*basis[b][f][h] ------------------------
__global__ __launch_bounds__(256) void wt_gemm(
    const float* __restrict__ basis, const float* __restrict__ comp,
    float* __restrict__ wt_nat) {
  __shared__ float cs[RR * NBASE];
  int tid = threadIdx.x;
  for (int i = tid; i < RR * NBASE; i += 256) cs[i] = comp[i];
  __syncthreads();
  long col = (long)blockIdx.x * 256 + tid;
  float acc[RR] = {};
  for (int b = 0; b < NBASE; ++b) {
    float v = basis[(long)b * 131072 + col];
#pragma unroll
    for (int r = 0; r < RR; ++r) acc[r] += cs[r * NBASE + b] * v;
  }
#pragma unroll
  for (int r = 0; r < RR; ++r) wt_nat[(long)r * 131072 + col] = acc[r];
}

// ---- wt_nat [16][512][256] (r,f,h) -> wtc[(r*256+h)][512] hi/lo --------------
__global__ __launch_bounds__(256) void wt_transpose(
    const float* __restrict__ wt_nat,
    __hip_bfloat16* __restrict__ hi, __hip_bfloat16* __restrict__ lo) {
  __shared__ float t[32][33];
  const int r = blockIdx.z;
  const int f0 = blockIdx.y * 32, h0 = blockIdx.x * 32;
  const int c = threadIdx.x & 31, rw = threadIdx.x >> 5;
  const float* src = wt_nat + ((long)r * 512 + f0) * 256 + h0;
#pragma unroll
  for (int i = 0; i < 4; ++i)
    t[rw + i * 8][c] = src[(long)(rw + i * 8) * 256 + c];
  __syncthreads();
#pragma unroll
  for (int i = 0; i < 4; ++i) {
    int hh = rw + i * 8;
    float v = t[c][hh];
    long orow = (long)(r * 256 + h0 + hh) * 512 + f0 + c;
    __hip_bfloat16 hv = __float2bfloat16(v);
    hi[orow] = hv;
    lo[orow] = __float2bfloat16(v - __bfloat162float(hv));
  }
}

// ---------------- fused dual-precision MFMA GEMM ------------------------------
// One K-pass: acc += Ahi@Bhi + Ahi@Blo (+ Alo@Bhi). 128x128 tile, BK=32,
// 4 waves, 16x16x32 bf16 MFMA, global_load_lds w=16. GROUP_M=8 block swizzle
// for A-slab L2 reuse.
__device__ __forceinline__ void gload_lds16(const void* g, void* l) {
  __builtin_amdgcn_global_load_lds(
      (const __attribute__((address_space(1))) unsigned int*)g,
      (__attribute__((address_space(3))) unsigned int*)l, 16, 0, 0);
}

__global__ __launch_bounds__(256) void mfma_dual(
    const __hip_bfloat16* __restrict__ A, const __hip_bfloat16* __restrict__ Alo,
    const __hip_bfloat16* __restrict__ Bt, const __hip_bfloat16* __restrict__ Btlo,
    const float* __restrict__ bias, float* __restrict__ C, float* __restrict__ Ct,
    __hip_bfloat16* __restrict__ Chi, __hip_bfloat16* __restrict__ Clo,
    int K, int ldc, long sA, long sB, long sC, int flags) {
  __shared__ __hip_bfloat16 Ah[128 * 32];
  __shared__ __hip_bfloat16 Bh[128 * 32];
  __shared__ __hip_bfloat16 Al[128 * 32];
  __shared__ __hip_bfloat16 Bl[128 * 32];
  const int tid = threadIdx.x;
  const int w = tid >> 6, lane = tid & 63;
  const long z = blockIdx.z;
  // GROUP_M=8 swizzle: consecutive blocks share an 8-row-block A slab.
  {
  }
  const int nbx = gridDim.x, nby = gridDim.y;
  const int pid = blockIdx.y * nbx + blockIdx.x;
  const int G = 8 * nbx;
  const int gid = pid / G;
  const int first = gid * 8;
  const int rows = min(nby - first, 8);
  const int by = first + (pid % G) % rows;
  const int bx = (pid % G) / rows;
  const long row0 = (long)by * 128, col0 = (long)bx * 128;
  const int wm = w & 1, wn = w >> 1;
  const int srow0 = (w * 128 + lane) >> 2;
  const int srow1 = (w * 128 + 64 + lane) >> 2;
  const int kch = (lane & 3) * 8;
  const int fr = lane & 15, q = lane >> 4;
  const bool hasAlo = (Alo != nullptr);
  const __hip_bfloat16* Az = A + z * sA;
  const __hip_bfloat16* Alz = hasAlo ? (Alo + z * sA) : nullptr;
  const __hip_bfloat16* Bz = Bt + z * sB;
  const __hip_bfloat16* Blz = Btlo + z * sB;
  const long aoff0 = (row0 + srow0) * K + kch, aoff1 = (row0 + srow1) * K + kch;
  const long boff0 = (col0 + srow0) * K + kch, boff1 = (col0 + srow1) * K + kch;
  f32x4 acc[4][4] = {};
  for (int k0 = 0; k0 < K; k0 += 32) {
    gload_lds16(Az + aoff0 + k0, Ah + w * 1024);
    gload_lds16(Az + aoff1 + k0, Ah + w * 1024 + 512);
    gload_lds16(Bz + boff0 + k0, Bh + w * 1024);
    gload_lds16(Bz + boff1 + k0, Bh + w * 1024 + 512);
    gload_lds16(Blz + boff0 + k0, Bl + w * 1024);
    gload_lds16(Blz + boff1 + k0, Bl + w * 1024 + 512);
    if (hasAlo) {
      gload_lds16(Alz + aoff0 + k0, Al + w * 1024);
      gload_lds16(Alz + aoff1 + k0, Al + w * 1024 + 512);
    }
    __syncthreads();
    bf16x8 ah[4], bh[4], bl[4];
#pragma unroll
    for (int i = 0; i < 4; ++i) {
      ah[i] = *(const bf16x8*)&Ah[(wm * 64 + i * 16 + fr) * 32 + q * 8];
      bh[i] = *(const bf16x8*)&Bh[(wn * 64 + i * 16 + fr) * 32 + q * 8];
      bl[i] = *(const bf16x8*)&Bl[(wn * 64 + i * 16 + fr) * 32 + q * 8];
    }
#pragma unroll
    for (int i = 0; i < 4; ++i)
#pragma unroll
      for (int j = 0; j < 4; ++j) {
        acc[i][j] = __builtin_amdgcn_mfma_f32_16x16x32_bf16(ah[i], bh[j], acc[i][j], 0, 0, 0);
        acc[i][j] = __builtin_amdgcn_mfma_f32_16x16x32_bf16(ah[i], bl[j], acc[i][j], 0, 0, 0);
      }
    if (hasAlo) {
      bf16x8 al[4];
#pragma unroll
      for (int i = 0; i < 4; ++i)
        al[i] = *(const bf16x8*)&Al[(wm * 64 + i * 16 + fr) * 32 + q * 8];
#pragma unroll
      for (int i = 0; i < 4; ++i)
#pragma unroll
        for (int j = 0; j < 4; ++j)
          acc[i][j] = __builtin_amdgcn_mfma_f32_16x16x32_bf16(al[i], bh[j], acc[i][j], 0, 0, 0);
    }
    __syncthreads();
  }
  const int cr = (lane >> 4) * 4, cc = lane & 15;
  float* Cz = C ? (C + z * sC) : nullptr;
  __hip_bfloat16* Chz = Chi ? (Chi + z * sC) : nullptr;
  __hip_bfloat16* Clz = Clo ? (Clo + z * sC) : nullptr;
#pragma unroll
  for (int i = 0; i < 4; ++i) {
    long rbase = row0 + wm * 64 + i * 16 + cr;
#pragma unroll
    for (int j = 0; j < 4; ++j) {
      long col = col0 + wn * 64 + j * 16 + cc;
      float bv = (flags & FLAG_BIAS) ? bias[col] : 0.f;
#pragma unroll
      for (int r = 0; r < 4; ++r) {
        float v = acc[i][j][r] + bv;
        if (flags & FLAG_RELU) v = fmaxf(v, 0.f);
        if (flags & FLAG_TANH) v = tanhf(v);
        if (flags & FLAG_SPLITOUT) {
          long off = (rbase + r) * ldc + col;
          __hip_bfloat16 hv = __float2bfloat16(v);
          Chz[off] = hv;
          Clz[off] = __float2bfloat16(v - __bfloat162float(hv));
        } else if ((flags & FLAG_TAILOUT) && col >= 4096) {
          Ct[(rbase + r) * 256 + (col - 4096)] = v;
        } else {
          Cz[(rbase + r) * ldc + col] = v;
        }
      }
    }
  }
}

// ---------------- edge kernels: CSR build + gathers ----------------------------
__global__ __launch_bounds__(256) void count_edges(
    const int* __restrict__ ei, const int* __restrict__ et, float* __restrict__ cnt) {
  int e = blockIdx.x * 256 + threadIdx.x;
  if (e < EE) atomicAdd(&cnt[ei[EE + e] * RR + et[e]], 1.0f);
}

__global__ __launch_bounds__(256) void scan_rowptr(
    const float* __restrict__ cntf, int* __restrict__ rowptr, int* __restrict__ fill) {
  __shared__ int part[256];
  int tid = threadIdx.x;
  int base = tid * 32;
  int local[32];
  int s = 0;
  for (int i = 0; i < 32; ++i) {
    local[i] = s;
    const float* c = &cntf[(base + i) * RR];
    int d = 0;
#pragma unroll
    for (int r = 0; r < RR; ++r) d += (int)c[r];
    s += d;
  }
  part[tid] = s;
  __syncthreads();
  for (int off = 1; off < 256; off <<= 1) {
    int v = (tid >= off) ? part[tid - off] : 0;
    __syncthreads();
    part[tid] += v;
    __syncthreads();
  }
  int prev = (tid == 0) ? 0 : part[tid - 1];
  for (int i = 0; i < 32; ++i) rowptr[base + i] = prev + local[i];
  if (tid == 255) rowptr[8192] = part[255];
  for (int i = tid; i < 8192; i += 256) fill[i] = 0;
}

__global__ __launch_bounds__(256) void edge_fill(
    const int* __restrict__ ei, const int* __restrict__ et,
    const int* __restrict__ rowptr, int* __restrict__ fill, int* __restrict__ eidx) {
  int e = blockIdx.x * 256 + threadIdx.x;
  if (e < EE) {
    int dst = ei[EE + e];
    int pos = rowptr[dst] + atomicAdd(&fill[dst], 1);
    eidx[pos] = ei[e] | (et[e] << 16);
  }
}

// out1 += mean-agg; also emit split into a2o1 cols 256:512 (A of out2 GEMM)
__global__ __launch_bounds__(256) void rgcn_gather(
    const int* __restrict__ rowptr, const int* __restrict__ eidx,
    const float* __restrict__ cntf, const float* __restrict__ xw,
    float* __restrict__ out1, __hip_bfloat16* __restrict__ a2o1_hi,
    __hip_bfloat16* __restrict__ a2o1_lo) {
  const int dst = blockIdx.x;
  const int h = threadIdx.x;
  __shared__ float inv[RR];
  __shared__ int se[256];
  if (h < RR) inv[h] = 1.0f / fmaxf(cntf[dst * RR + h], 1.0f);
  const int beg = rowptr[dst], end = rowptr[dst + 1];
  float acc = 0.f;
  for (int c0 = beg; c0 < end; c0 += 256) {
    int n = min(256, end - c0);
    __syncthreads();
    if (h < n) se[h] = eidx[c0 + h];
    __syncthreads();
    for (int i = 0; i < n; ++i) {
      int pk = se[i];
      int src = pk & 0xFFFF, r = pk >> 16;
      acc += xw[((long)src << 12) + (r << 8) + h] * inv[r];
    }
  }
  float tot = out1[((long)dst << 8) + h] + acc;
  out1[((long)dst << 8) + h] = tot;
  __hip_bfloat16 hv = __float2bfloat16(tot);
  long d = (long)dst * 512 + 256 + h;
  a2o1_hi[d] = hv;
  a2o1_lo[d] = __float2bfloat16(tot - __bfloat162float(hv));
}

// a2o1 cols 0:256 = sum_{src->dst} out1[src] (split)
__global__ __launch_bounds__(256) void graphconv_gather(
    const int* __restrict__ rowptr, const int* __restrict__ eidx,
    const float* __restrict__ out1, __hip_bfloat16* __restrict__ a2o1_hi,
    __hip_bfloat16* __restrict__ a2o1_lo) {
  const int dst = blockIdx.x;
  const int h = threadIdx.x;
  __shared__ int se[256];
  const int beg = rowptr[dst], end = rowptr[dst + 1];
  float acc = 0.f;
  for (int c0 = beg; c0 < end; c0 += 256) {
    int n = min(256, end - c0);
    __syncthreads();
    if (h < n) se[h] = eidx[c0 + h];
    __syncthreads();
    for (int i = 0; i < n; ++i)
      acc += out1[((long)(se[i] & 0xFFFF) << 8) + h];
  }
  __hip_bfloat16 hv = __float2bfloat16(acc);
  long d = (long)dst * 512 + h;
  a2o1_hi[d] = hv;
  a2o1_lo[d] = __float2bfloat16(acc - __bfloat162float(hv));
}

// ---------------- softmax over last dim (256), bf16 weights out ---------------
__global__ __launch_bounds__(256) void softmax256(const float* __restrict__ S,
                                                  __hip_bfloat16* __restrict__ Ab) {
  __shared__ float red[256];
  long row = blockIdx.x;
  const float* p = S + row * 256;
  int t = threadIdx.x;
  float v = p[t];
  red[t] = v;
  __syncthreads();
  for (int s = 128; s > 0; s >>= 1) {
    if (t < s) red[t] = fmaxf(red[t], red[t + s]);
    __syncthreads();
  }
  float m = red[0];
  __syncthreads();
  float e = __expf(v - m);
  red[t] = e;
  __syncthreads();
  for (int s = 128; s > 0; s >>= 1) {
    if (t < s) red[t] += red[t + s];
    __syncthreads();
  }
  Ab[row * 256 + t] = __float2bfloat16(e / red[0]);
}

// ---------------- logits + log_softmax over batch axis (faithful dim=1) -------
__global__ __launch_bounds__(256) void logits_lsm(
    const float* __restrict__ hidden, const float* __restrict__ w_fc,
    const float* __restrict__ b_fc, void* __restrict__ out_v,
    const int* __restrict__ flag) {
  __shared__ float wf[256 * 7];
  __shared__ float lg[224];
  __shared__ float corr[7];
  int t = blockIdx.x;
  int tid = threadIdx.x;
  for (int i = tid; i < 256 * 7; i += 256) wf[i] = w_fc[i];
  __syncthreads();
  if (tid < 224) {
    int b = tid / 7, c = tid % 7;
    const float* hr = hidden + ((long)((b << 8) + t) << 8);
    float s = b_fc[c];
    for (int k = 0; k < 256; ++k) s += hr[k] * wf[k * 7 + c];
    lg[tid] = s;
  }
  __syncthreads();
  if (tid < 7) {
    float m = -1e30f;
    for (int b = 0; b < BB; ++b) m = fmaxf(m, lg[b * 7 + tid]);
    float sum = 0.f;
    for (int b = 0; b < BB; ++b) sum += __expf(lg[b * 7 + tid] - m);
    corr[tid] = m + logf(sum);
  }
  __syncthreads();
  if (tid < 224) {
    float v = lg[tid] - corr[tid % 7];
    if (flag[0]) ((float*)out_v)[t * 224 + tid] = v;
    else ((__hip_bfloat16*)out_v)[t * 224 + tid] = __float2bfloat16(v);
  }
}

extern "C" void kernel_launch(void* const* d_in, const int* in_sizes, int n_in,
                              void* d_out, int out_size, void* d_ws, size_t ws_size,
                              hipStream_t stream) {
  const int* ei = (const int*)d_in[1];
  const int* et = (const int*)d_in[3];

  float* ws = (float*)d_ws;
  int* flag = (int*)d_ws;
  float* p = ws + 16;
  auto alloc = [&](long nf) { float* r = p; p += nf; return r; };
  float* w_fc_f = alloc(1792);
  float* b_rel_f = alloc(256);
  float* biasx = alloc(4352);                                    // [0..4095]=0, tail=bias1
  float* b_att_f = alloc(768);
  float* b_lin_f = alloc(256);
  float* b_fc_f = alloc(16);
  __hip_bfloat16* wlin_hi = (__hip_bfloat16*)alloc(98304);       // [256][768]
  __hip_bfloat16* wlin_lo = (__hip_bfloat16*)alloc(98304);
  __hip_bfloat16* x_hi = (__hip_bfloat16*)alloc(2097152);        // [8192][512]
  __hip_bfloat16* x_lo = (__hip_bfloat16*)alloc(2097152);
  __hip_bfloat16* watt_hi = (__hip_bfloat16*)alloc(294912);      // [768][768]
  __hip_bfloat16* watt_lo = (__hip_bfloat16*)alloc(294912);
  __hip_bfloat16* wrr_hi = (__hip_bfloat16*)alloc(65536);        // [256][512] = [w_rel;w_root]^T
  __hip_bfloat16* wrr_lo = (__hip_bfloat16*)alloc(65536);
  __hip_bfloat16* wtc_hi = (__hip_bfloat16*)alloc(1114112);      // [4352][512]
  __hip_bfloat16* wtc_lo = (__hip_bfloat16*)alloc(1114112);
  float* basis_f = alloc(3932160);
  float* comp_f = alloc(512);
  float* xw = alloc(33554432);   // fp32 [8192][4096]; overlays below
  float* cnt = alloc(131072);
  float* out1 = alloc(2097152);
  __hip_bfloat16* a2o1_hi = (__hip_bfloat16*)alloc(2097152);     // [8192][512]
  __hip_bfloat16* a2o1_lo = (__hip_bfloat16*)alloc(2097152);
  float* hidden = alloc(2097152);
  int* rowptr = (int*)alloc(8208);
  int* fillc = (int*)alloc(8192);
  int* eidx = (int*)alloc(262144);
  // wt_nat overlays head of xw (consumed by wt_transpose before xw is written)
  float* wt_nat = xw;                                            // [16][512][256]
  // phase B overlays the (consumed) xw region
  float* em = xw;
  __hip_bfloat16* em_hi = (__hip_bfloat16*)(em + 6291456);       // [8192][768]
  __hip_bfloat16* em_lo = (__hip_bfloat16*)(em + 9437184);
  __hip_bfloat16* X_hi = (__hip_bfloat16*)(em + 12582912);
  __hip_bfloat16* X_lo = (__hip_bfloat16*)(em + 15728640);
  float* scores = em + 18874368;                                 // 2,097,152 f
  __hip_bfloat16* a_b16 = (__hip_bfloat16*)(em + 20971520);      // 1,048,576 f
  __hip_bfloat16* att_hi = (__hip_bfloat16*)(em + 22020096);
  __hip_bfloat16* att_lo = (__hip_bfloat16*)(em + 25165824);
  // emT overlays dead em-fp32 head
  __hip_bfloat16* emT_hi = (__hip_bfloat16*)em;
  __hip_bfloat16* emT_lo = (__hip_bfloat16*)(em + 3145728);

  // 0. dtype detect + single fused conversion launch
  detect_dtype<<<1, 256, 0, stream>>>((const unsigned short*)d_in[0], flag);
  ConvTable T{};
  long tot = 0;
  int ns = 0;
  auto seg = [&](const void* s, float* d, __hip_bfloat16* hi, __hip_bfloat16* lo,
                 int n, int z) {
    T.seg[ns].src = s; T.seg[ns].dst = d; T.seg[ns].hi = hi; T.seg[ns].lo = lo;
    T.seg[ns].n = n; T.seg[ns].zero = z; ns++; tot += n;
  };
  seg(d_in[0], nullptr, x_hi, x_lo, NN * FF, 0);
  seg(d_in[8], basis_f, nullptr, nullptr, NBASE * FF * HH, 0);
  seg(d_in[9], comp_f, nullptr, nullptr, RR * NBASE, 0);
  seg(d_in[13], b_rel_f, nullptr, nullptr, HH, 0);
  seg(d_in[16], b_att_f, nullptr, nullptr, DD, 0);
  seg(d_in[18], b_lin_f, nullptr, nullptr, HH, 0);
  seg(d_in[19], w_fc_f, nullptr, nullptr, HH * CC, 0);
  seg(d_in[20], b_fc_f, nullptr, nullptr, CC, 0);
  seg(nullptr, biasx, nullptr, nullptr, 4096, 1);
  seg(d_in[11], biasx + 4096, nullptr, nullptr, HH, 0);
  T.count = ns;
  T.total = tot;
  conv_all<<<4096, 256, 0, stream>>>(T, flag);
  split_t_b16<<<2048, 256, 0, stream>>>(d_in[15], watt_hi, watt_lo, DD, DD, DD, 0, flag);
  split_t_b16<<<768, 256, 0, stream>>>(d_in[17], wlin_hi, wlin_lo, DD, HH, DD, 0, flag);
  split_t_b16<<<512, 256, 0, stream>>>(d_in[10], wtc_hi + 4096 * 512,
                                       wtc_lo + 4096 * 512, FF, HH, FF, 0, flag);
  split_t_b16<<<256, 256, 0, stream>>>(d_in[12], wrr_hi, wrr_lo, HH, HH, 512, 0, flag);
  split_t_b16<<<256, 256, 0, stream>>>(d_in[14], wrr_hi, wrr_lo, HH, HH, 512, 256, flag);

  // 1. Wt: coalesced GEMM into natural layout, then LDS-tiled transpose + split
  wt_gemm<<<131072 / 256, 256, 0, stream>>>(basis_f, comp_f, wt_nat);
  wt_transpose<<<dim3(8, 16, 16), 256, 0, stream>>>(wt_nat, wtc_hi, wtc_lo);
  // 2. merged xw|out1 = x @ [W | root1] + [0 | bias1]  (cols>=4096 -> out1)
  mfma_dual<<<dim3(34, 64, 1), 256, 0, stream>>>(
      x_hi, x_lo, wtc_hi, wtc_lo, biasx, xw, out1, nullptr, nullptr, FF, 4096,
      0, 0, 0, FLAG_BIAS | FLAG_TAILOUT);
  // 3. CSR build
  hipMemsetAsync(cnt, 0, 131072 * sizeof(float), stream);
  count_edges<<<EE / 256, 256, 0, stream>>>(ei, et, cnt);
  scan_rowptr<<<1, 256, 0, stream>>>(cnt, rowptr, fillc);
  edge_fill<<<EE / 256, 256, 0, stream>>>(ei, et, rowptr, fillc, eidx);
  // 4/5. aggregations (gather); emit [agg2|out1] hi/lo as out2-GEMM A operand
  rgcn_gather<<<NN, 256, 0, stream>>>(rowptr, eidx, cnt, xw, out1, a2o1_hi, a2o1_lo);
  graphconv_gather<<<NN, 256, 0, stream>>>(rowptr, eidx, out1, a2o1_hi, a2o1_lo);
  // 6. em cols 0:512 = x (split); cols 512:768 = out2 via split-MFMA
  copy_xsplit<<<(NN * FF) / 256, 256, 0, stream>>>(x_hi, x_lo, em_hi, em_lo);
  mfma_dual<<<dim3(2, 64, 1), 256, 0, stream>>>(
      a2o1_hi, a2o1_lo, wrr_hi, wrr_lo, b_rel_f, nullptr, nullptr,
      em_hi + 512, em_lo + 512, 512, DD, 0, 0, 0, FLAG_BIAS | FLAG_SPLITOUT);
  // 6b. emT (for att B-operand)
  transpose_b16<<<dim3(24, 8, 32), 256, 0, stream>>>(em_hi, emT_hi);
  transpose_b16<<<dim3(24, 8, 32), 256, 0, stream>>>(em_lo, emT_lo);
  // 7. X = emotions @ w_att + b_att -> split out
  mfma_dual<<<dim3(6, 64, 1), 256, 0, stream>>>(
      em_hi, em_lo, watt_hi, watt_lo, b_att_f, nullptr, nullptr, X_hi, X_lo, DD, DD,
      0, 0, 0, FLAG_BIAS | FLAG_SPLITOUT);
  // 8. scores = tanh(X_b . em_b^T) (batched, fp32 out)
  mfma_dual<<<dim3(2, 2, BB), 256, 0, stream>>>(
      X_hi, X_lo, em_hi, em_lo, nullptr, scores, nullptr, nullptr, nullptr, DD, LL,
      (long)LL * DD, (long)LL * DD, (long)LL * LL, FLAG_TANH);
  // 9. softmax over s -> bf16 attention weights
  softmax256<<<BB * LL, 256, 0, stream>>>(scores, a_b16);
  // 10. att_b = a_b @ em_b (batched, split out)
  mfma_dual<<<dim3(6, 2, BB), 256, 0, stream>>>(
      a_b16, nullptr, emT_hi, emT_lo, nullptr, nullptr, nullptr, att_hi, att_lo, LL, DD,
      (long)LL * LL, (long)LL * DD, (long)LL * DD, FLAG_SPLITOUT);
  // 11. hidden = relu(att @ w_lin + b_lin)
  mfma_dual<<<dim3(2, 64, 1), 256, 0, stream>>>(
      att_hi, att_lo, wlin_hi, wlin_lo, b_lin_f, hidden, nullptr, nullptr, nullptr,
      DD, HH, 0, 0, 0, FLAG_BIAS | FLAG_RELU);
  // 12. logits + log_softmax over batch axis
  logits_lsm<<<LL, 256, 0, stream>>>(hidden, w_fc_f, b_fc_f, d_out, flag);
}

// Round 11
// 652.901 us; speedup vs baseline: 1.1969x; 1.0684x over previous
//
#include <hip/hip_runtime.h>
#include <hip/hip_bf16.h>

// Problem constants (fixed by setup_inputs)
#define NN 8192
#define FF 512
#define HH 256
#define RR 16
#define BB 32
#define LL 256
#define CC 7
#define EE 262144
#define NBASE 30
#define DD 768

constexpr int FLAG_BIAS = 1, FLAG_RELU = 4, FLAG_TANH = 8,
              FLAG_SPLITOUT = 16, FLAG_TAILOUT = 32;

typedef __attribute__((ext_vector_type(8))) short bf16x8;
typedef __attribute__((ext_vector_type(4))) float f32x4;

// ------------- dtype detection (robustness) -----------------------------------
__global__ __launch_bounds__(256) void detect_dtype(const unsigned short* __restrict__ xs,
                                                    int* __restrict__ flag) {
  __shared__ int red[256];
  int cnt = 0;
  for (int i = threadIdx.x * 2; i < 8192; i += 512) {
    unsigned short u = xs[i];
    int e = (u >> 7) & 0xFF;
    if (e >= 0xC0) cnt++;
  }
  red[threadIdx.x] = cnt;
  __syncthreads();
  for (int s = 128; s > 0; s >>= 1) {
    if (threadIdx.x < s) red[threadIdx.x] += red[threadIdx.x + s];
    __syncthreads();
  }
  if (threadIdx.x == 0) flag[0] = (red[0] > 16) ? 1 : 0;  // 1 = fp32 data
}

// ------------- fused conversion: all small tensors in one launch ---------------
struct ConvSeg {
  const void* src;
  float* dst;
  __hip_bfloat16* hi;
  __hip_bfloat16* lo;
  int n;
  int zero;
};
struct ConvTable {
  ConvSeg seg[12];
  int count;
  long total;
};

__global__ __launch_bounds__(256) void conv_all(ConvTable t, const int* __restrict__ flag) {
  const int fp32 = flag[0];
  for (long i = (long)blockIdx.x * 256 + threadIdx.x; i < t.total;
       i += (long)gridDim.x * 256) {
    long off = i;
    int s = 0;
    while (off >= t.seg[s].n) { off -= t.seg[s].n; s++; }
    const ConvSeg& sg = t.seg[s];
    float v = 0.f;
    if (!sg.zero)
      v = fp32 ? ((const float*)sg.src)[off]
               : __bfloat162float(((const __hip_bfloat16*)sg.src)[off]);
    if (sg.dst) sg.dst[off] = v;
    if (sg.hi) {
      __hip_bfloat16 h = __float2bfloat16(v);
      sg.hi[off] = h;
      sg.lo[off] = __float2bfloat16(v - __bfloat162float(h));
    }
  }
}

// ------------- fused transpose+split for all weight matrices -------------------
struct TSeg {
  const void* src;
  __hip_bfloat16* hi;
  __hip_bfloat16* lo;
  int R, C, ld, off;
};
struct TTable {
  TSeg seg[6];
  int count;
  long total;
};

__global__ __launch_bounds__(256) void split_t_all(TTable t, const int* __restrict__ flag) {
  const int fp32 = flag[0];
  for (long i = (long)blockIdx.x * 256 + threadIdx.x; i < t.total;
       i += (long)gridDim.x * 256) {
    long off = i;
    int s = 0;
    while (off >= (long)t.seg[s].R * t.seg[s].C) { off -= (long)t.seg[s].R * t.seg[s].C; s++; }
    const TSeg& sg = t.seg[s];
    int r = (int)(off % sg.R), c = (int)(off / sg.R);
    float v = fp32 ? ((const float*)sg.src)[(long)r * sg.C + c]
                   : __bfloat162float(((const __hip_bfloat16*)sg.src)[(long)r * sg.C + c]);
    __hip_bfloat16 h = __float2bfloat16(v);
    long d = (long)c * sg.ld + sg.off + r;
    sg.hi[d] = h;
    sg.lo[d] = __float2bfloat16(v - __bfloat162float(h));
  }
}

// copy x_hi/x_lo [8192][512] into em_hi/lo [8192][768] cols 0:512
__global__ __launch_bounds__(256) void copy_xsplit(
    const __hip_bfloat16* __restrict__ xh, const __hip_bfloat16* __restrict__ xl,
    __hip_bfloat16* __restrict__ eh, __hip_bfloat16* __restrict__ el) {
  int idx = blockIdx.x * 256 + threadIdx.x;  // 8192*512
  int n = idx >> 9, f = idx & 511;
  long d = (long)n * DD + f;
  eh[d] = xh[idx];
  el[d] = xl[idx];
}

// batched bf16 transpose: src [z][S][D] -> dst [z][D][S]  (S=256, D=768)
__global__ __launch_bounds__(256) void transpose_b16(
    const __hip_bfloat16* __restrict__ src, __hip_bfloat16* __restrict__ dst) {
  __shared__ __hip_bfloat16 t[32][33];
  const long b = blockIdx.z;
  const int d0 = blockIdx.x * 32, s0 = blockIdx.y * 32;
  const int c = threadIdx.x & 31, rw = threadIdx.x >> 5;
  const __hip_bfloat16* sp = src + b * (LL * DD);
  __hip_bfloat16* dp = dst + b * (LL * DD);
#pragma unroll
  for (int i = 0; i < 4; ++i)
    t[rw + i * 8][c] = sp[(long)(s0 + rw + i * 8) * DD + d0 + c];
  __syncthreads();
#pragma unroll
  for (int i = 0; i < 4; ++i)
    dp[(long)(d0 + rw + i * 8) * LL + s0 + c] = t[c][rw + i * 8];
}

// ---- wt_nat[r][f][h] = sum_b comp[r,b]*basis[b][f][h] ------------------------
__global__ __launch_bounds__(256) void wt_gemm(
    const float* __restrict__ basis, const float* __restrict__ comp,
    float* __restrict__ wt_nat) {
  __shared__ float cs[RR * NBASE];
  int tid = threadIdx.x;
  for (int i = tid; i < RR * NBASE; i += 256) cs[i] = comp[i];
  __syncthreads();
  long col = (long)blockIdx.x * 256 + tid;
  float acc[RR] = {};
  for (int b = 0; b < NBASE; ++b) {
    float v = basis[(long)b * 131072 + col];
#pragma unroll
    for (int r = 0; r < RR; ++r) acc[r] += cs[r * NBASE + b] * v;
  }
#pragma unroll
  for (int r = 0; r < RR; ++r) wt_nat[(long)r * 131072 + col] = acc[r];
}

// ---- wt_nat [16][512][256] (r,f,h) -> wtc[(r*256+h)][512] hi/lo --------------
__global__ __launch_bounds__(256) void wt_transpose(
    const float* __restrict__ wt_nat,
    __hip_bfloat16* __restrict__ hi, __hip_bfloat16* __restrict__ lo) {
  __shared__ float t[32][33];
  const int r = blockIdx.z;
  const int f0 = blockIdx.y * 32, h0 = blockIdx.x * 32;
  const int c = threadIdx.x & 31, rw = threadIdx.x >> 5;
  const float* src = wt_nat + ((long)r * 512 + f0) * 256 + h0;
#pragma unroll
  for (int i = 0; i < 4; ++i)
    t[rw + i * 8][c] = src[(long)(rw + i * 8) * 256 + c];
  __syncthreads();
#pragma unroll
  for (int i = 0; i < 4; ++i) {
    int hh = rw + i * 8;
    float v = t[c][hh];
    long orow = (long)(r * 256 + h0 + hh) * 512 + f0 + c;
    __hip_bfloat16 hv = __float2bfloat16(v);
    hi[orow] = hv;
    lo[orow] = __float2bfloat16(v - __bfloat162float(hv));
  }
}

// ---------------- fused dual-precision MFMA GEMM ------------------------------
// One K-pass: acc += Ahi@Bhi + Ahi@Blo (+ Alo@Bhi). 128x128 tile, BK=32,
// 4 waves, 16x16x32 bf16 MFMA, global_load_lds w=16.
// __launch_bounds__(256,3): cap unified VGPR at 170 to get 3 blocks/CU.
__device__ __forceinline__ void gload_lds16(const void* g, void* l) {
  __builtin_amdgcn_global_load_lds(
      (const __attribute__((address_space(1))) unsigned int*)g,
      (__attribute__((address_space(3))) unsigned int*)l, 16, 0, 0);
}

__global__ __launch_bounds__(256, 3) void mfma_dual(
    const __hip_bfloat16* __restrict__ A, const __hip_bfloat16* __restrict__ Alo,
    const __hip_bfloat16* __restrict__ Bt, const __hip_bfloat16* __restrict__ Btlo,
    const float* __restrict__ bias, float* __restrict__ C, float* __restrict__ Ct,
    __hip_bfloat16* __restrict__ Chi, __hip_bfloat16* __restrict__ Clo,
    int K, int ldc, long sA, long sB, long sC, int flags) {
  __shared__ __hip_bfloat16 Ah[128 * 32];
  __shared__ __hip_bfloat16 Bh[128 * 32];
  __shared__ __hip_bfloat16 Al[128 * 32];
  __shared__ __hip_bfloat16 Bl[128 * 32];
  const int tid = threadIdx.x;
  const int w = tid >> 6, lane = tid & 63;
  const long z = blockIdx.z;
  const long row0 = (long)blockIdx.y * 128, col0 = (long)blockIdx.x * 128;
  const int wm = w & 1, wn = w >> 1;
  const int srow0 = (w * 128 + lane) >> 2;
  const int srow1 = (w * 128 + 64 + lane) >> 2;
  const int kch = (lane & 3) * 8;
  const int fr = lane & 15, q = lane >> 4;
  const bool hasAlo = (Alo != nullptr);
  const __hip_bfloat16* Az = A + z * sA;
  const __hip_bfloat16* Alz = hasAlo ? (Alo + z * sA) : nullptr;
  const __hip_bfloat16* Bz = Bt + z * sB;
  const __hip_bfloat16* Blz = Btlo + z * sB;
  const long aoff0 = (row0 + srow0) * K + kch, aoff1 = (row0 + srow1) * K + kch;
  const long boff0 = (col0 + srow0) * K + kch, boff1 = (col0 + srow1) * K + kch;
  f32x4 acc[4][4] = {};
  for (int k0 = 0; k0 < K; k0 += 32) {
    gload_lds16(Az + aoff0 + k0, Ah + w * 1024);
    gload_lds16(Az + aoff1 + k0, Ah + w * 1024 + 512);
    gload_lds16(Bz + boff0 + k0, Bh + w * 1024);
    gload_lds16(Bz + boff1 + k0, Bh + w * 1024 + 512);
    gload_lds16(Blz + boff0 + k0, Bl + w * 1024);
    gload_lds16(Blz + boff1 + k0, Bl + w * 1024 + 512);
    if (hasAlo) {
      gload_lds16(Alz + aoff0 + k0, Al + w * 1024);
      gload_lds16(Alz + aoff1 + k0, Al + w * 1024 + 512);
    }
    __syncthreads();
    bf16x8 ah[4], bh[4], bl[4];
#pragma unroll
    for (int i = 0; i < 4; ++i) {
      ah[i] = *(const bf16x8*)&Ah[(wm * 64 + i * 16 + fr) * 32 + q * 8];
      bh[i] = *(const bf16x8*)&Bh[(wn * 64 + i * 16 + fr) * 32 + q * 8];
      bl[i] = *(const bf16x8*)&Bl[(wn * 64 + i * 16 + fr) * 32 + q * 8];
    }
#pragma unroll
    for (int i = 0; i < 4; ++i)
#pragma unroll
      for (int j = 0; j < 4; ++j) {
        acc[i][j] = __builtin_amdgcn_mfma_f32_16x16x32_bf16(ah[i], bh[j], acc[i][j], 0, 0, 0);
        acc[i][j] = __builtin_amdgcn_mfma_f32_16x16x32_bf16(ah[i], bl[j], acc[i][j], 0, 0, 0);
      }
    if (hasAlo) {
      bf16x8 al[4];
#pragma unroll
      for (int i = 0; i < 4; ++i)
        al[i] = *(const bf16x8*)&Al[(wm * 64 + i * 16 + fr) * 32 + q * 8];
#pragma unroll
      for (int i = 0; i < 4; ++i)
#pragma unroll
        for (int j = 0; j < 4; ++j)
          acc[i][j] = __builtin_amdgcn_mfma_f32_16x16x32_bf16(al[i], bh[j], acc[i][j], 0, 0, 0);
    }
    __syncthreads();
  }
  const int cr = (lane >> 4) * 4, cc = lane & 15;
  float* Cz = C ? (C + z * sC) : nullptr;
  __hip_bfloat16* Chz = Chi ? (Chi + z * sC) : nullptr;
  __hip_bfloat16* Clz = Clo ? (Clo + z * sC) : nullptr;
#pragma unroll
  for (int i = 0; i < 4; ++i) {
    long rbase = row0 + wm * 64 + i * 16 + cr;
#pragma unroll
    for (int j = 0; j < 4; ++j) {
      long col = col0 + wn * 64 + j * 16 + cc;
      float bv = (flags & FLAG_BIAS) ? bias[col] : 0.f;
#pragma unroll
      for (int r = 0; r < 4; ++r) {
        float v = acc[i][j][r] + bv;
        if (flags & FLAG_RELU) v = fmaxf(v, 0.f);
        if (flags & FLAG_TANH) v = tanhf(v);
        if (flags & FLAG_SPLITOUT) {
          long off = (rbase + r) * ldc + col;
          __hip_bfloat16 hv = __float2bfloat16(v);
          Chz[off] = hv;
          Clz[off] = __float2bfloat16(v - __bfloat162float(hv));
        } else if ((flags & FLAG_TAILOUT) && col >= 4096) {
          Ct[(rbase + r) * 256 + (col - 4096)] = v;
        } else {
          Cz[(rbase + r) * ldc + col] = v;
        }
      }
    }
  }
}

// ---------------- edge kernels: CSR build + gathers ----------------------------
__global__ __launch_bounds__(256) void count_edges(
    const int* __restrict__ ei, const int* __restrict__ et, float* __restrict__ cnt) {
  int e = blockIdx.x * 256 + threadIdx.x;
  if (e < EE) atomicAdd(&cnt[ei[EE + e] * RR + et[e]], 1.0f);
}

__global__ __launch_bounds__(256) void scan_rowptr(
    const float* __restrict__ cntf, int* __restrict__ rowptr, int* __restrict__ fill) {
  __shared__ int part[256];
  int tid = threadIdx.x;
  int base = tid * 32;
  int local[32];
  int s = 0;
  for (int i = 0; i < 32; ++i) {
    local[i] = s;
    const float* c = &cntf[(base + i) * RR];
    int d = 0;
#pragma unroll
    for (int r = 0; r < RR; ++r) d += (int)c[r];
    s += d;
  }
  part[tid] = s;
  __syncthreads();
  for (int off = 1; off < 256; off <<= 1) {
    int v = (tid >= off) ? part[tid - off] : 0;
    __syncthreads();
    part[tid] += v;
    __syncthreads();
  }
  int prev = (tid == 0) ? 0 : part[tid - 1];
  for (int i = 0; i < 32; ++i) rowptr[base + i] = prev + local[i];
  if (tid == 255) rowptr[8192] = part[255];
  for (int i = tid; i < 8192; i += 256) fill[i] = 0;
}

__global__ __launch_bounds__(256) void edge_fill(
    const int* __restrict__ ei, const int* __restrict__ et,
    const int* __restrict__ rowptr, int* __restrict__ fill, int* __restrict__ eidx) {
  int e = blockIdx.x * 256 + threadIdx.x;
  if (e < EE) {
    int dst = ei[EE + e];
    int pos = rowptr[dst] + atomicAdd(&fill[dst], 1);
    eidx[pos] = ei[e] | (et[e] << 16);
  }
}

// out1 += mean-agg; also emit split into a2o1 cols 256:512 (A of out2 GEMM)
__global__ __launch_bounds__(256) void rgcn_gather(
    const int* __restrict__ rowptr, const int* __restrict__ eidx,
    const float* __restrict__ cntf, const float* __restrict__ xw,
    float* __restrict__ out1, __hip_bfloat16* __restrict__ a2o1_hi,
    __hip_bfloat16* __restrict__ a2o1_lo) {
  const int dst = blockIdx.x;
  const int h = threadIdx.x;
  __shared__ float inv[RR];
  __shared__ int se[256];
  if (h < RR) inv[h] = 1.0f / fmaxf(cntf[dst * RR + h], 1.0f);
  const int beg = rowptr[dst], end = rowptr[dst + 1];
  float acc = 0.f;
  for (int c0 = beg; c0 < end; c0 += 256) {
    int n = min(256, end - c0);
    __syncthreads();
    if (h < n) se[h] = eidx[c0 + h];
    __syncthreads();
    for (int i = 0; i < n; ++i) {
      int pk = se[i];
      int src = pk & 0xFFFF, r = pk >> 16;
      acc += xw[((long)src << 12) + (r << 8) + h] * inv[r];
    }
  }
  float tot = out1[((long)dst << 8) + h] + acc;
  out1[((long)dst << 8) + h] = tot;
  __hip_bfloat16 hv = __float2bfloat16(tot);
  long d = (long)dst * 512 + 256 + h;
  a2o1_hi[d] = hv;
  a2o1_lo[d] = __float2bfloat16(tot - __bfloat162float(hv));
}

// a2o1 cols 0:256 = sum_{src->dst} out1[src] (split)
__global__ __launch_bounds__(256) void graphconv_gather(
    const int* __restrict__ rowptr, const int* __restrict__ eidx,
    const float* __restrict__ out1, __hip_bfloat16* __restrict__ a2o1_hi,
    __hip_bfloat16* __restrict__ a2o1_lo) {
  const int dst = blockIdx.x;
  const int h = threadIdx.x;
  __shared__ int se[256];
  const int beg = rowptr[dst], end = rowptr[dst + 1];
  float acc = 0.f;
  for (int c0 = beg; c0 < end; c0 += 256) {
    int n = min(256, end - c0);
    __syncthreads();
    if (h < n) se[h] = eidx[c0 + h];
    __syncthreads();
    for (int i = 0; i < n; ++i)
      acc += out1[((long)(se[i] & 0xFFFF) << 8) + h];
  }
  __hip_bfloat16 hv = __float2bfloat16(acc);
  long d = (long)dst * 512 + h;
  a2o1_hi[d] = hv;
  a2o1_lo[d] = __float2bfloat16(acc - __bfloat162float(hv));
}

// ---------------- softmax over last dim (256), bf16 weights out ---------------
__global__ __launch_bounds__(256) void softmax256(const float* __restrict__ S,
                                                  __hip_bfloat16* __restrict__ Ab) {
  __shared__ float red[256];
  long row = blockIdx.x;
  const float* p = S + row * 256;
  int t = threadIdx.x;
  float v = p[t];
  red[t] = v;
  __syncthreads();
  for (int s = 128; s > 0; s >>= 1) {
    if (t < s) red[t] = fmaxf(red[t], red[t + s]);
    __syncthreads();
  }
  float m = red[0];
  __syncthreads();
  float e = __expf(v - m);
  red[t] = e;
  __syncthreads();
  for (int s = 128; s > 0; s >>= 1) {
    if (t < s) red[t] += red[t + s];
    __syncthreads();
  }
  Ab[row * 256 + t] = __float2bfloat16(e / red[0]);
}

// ---------------- logits + log_softmax over batch axis (faithful dim=1) -------
__global__ __launch_bounds__(256) void logits_lsm(
    const float* __restrict__ hidden, const float* __restrict__ w_fc,
    const float* __restrict__ b_fc, void* __restrict__ out_v,
    const int* __restrict__ flag) {
  __shared__ float wf[256 * 7];
  __shared__ float lg[224];
  __shared__ float corr[7];
  int t = blockIdx.x;
  int tid = threadIdx.x;
  for (int i = tid; i < 256 * 7; i += 256) wf[i] = w_fc[i];
  __syncthreads();
  if (tid < 224) {
    int b = tid / 7, c = tid % 7;
    const float* hr = hidden + ((long)((b << 8) + t) << 8);
    float s = b_fc[c];
    for (int k = 0; k < 256; ++k) s += hr[k] * wf[k * 7 + c];
    lg[tid] = s;
  }
  __syncthreads();
  if (tid < 7) {
    float m = -1e30f;
    for (int b = 0; b < BB; ++b) m = fmaxf(m, lg[b * 7 + tid]);
    float sum = 0.f;
    for (int b = 0; b < BB; ++b) sum += __expf(lg[b * 7 + tid] - m);
    corr[tid] = m + logf(sum);
  }
  __syncthreads();
  if (tid < 224) {
    float v = lg[tid] - corr[tid % 7];
    if (flag[0]) ((float*)out_v)[t * 224 + tid] = v;
    else ((__hip_bfloat16*)out_v)[t * 224 + tid] = __float2bfloat16(v);
  }
}

extern "C" void kernel_launch(void* const* d_in, const int* in_sizes, int n_in,
                              void* d_out, int out_size, void* d_ws, size_t ws_size,
                              hipStream_t stream) {
  const int* ei = (const int*)d_in[1];
  const int* et = (const int*)d_in[3];

  float* ws = (float*)d_ws;
  int* flag = (int*)d_ws;
  float* p = ws + 16;
  auto alloc = [&](long nf) { float* r = p; p += nf; return r; };
  float* w_fc_f = alloc(1792);
  float* b_rel_f = alloc(256);
  float* biasx = alloc(4352);                                    // [0..4095]=0, tail=bias1
  float* b_att_f = alloc(768);
  float* b_lin_f = alloc(256);
  float* b_fc_f = alloc(16);
  __hip_bfloat16* wlin_hi = (__hip_bfloat16*)alloc(98304);       // [256][768]
  __hip_bfloat16* wlin_lo = (__hip_bfloat16*)alloc(98304);
  __hip_bfloat16* x_hi = (__hip_bfloat16*)alloc(2097152);        // [8192][512]
  __hip_bfloat16* x_lo = (__hip_bfloat16*)alloc(2097152);
  __hip_bfloat16* watt_hi = (__hip_bfloat16*)alloc(294912);      // [768][768]
  __hip_bfloat16* watt_lo = (__hip_bfloat16*)alloc(294912);
  __hip_bfloat16* wrr_hi = (__hip_bfloat16*)alloc(65536);        // [256][512] = [w_rel;w_root]^T
  __hip_bfloat16* wrr_lo = (__hip_bfloat16*)alloc(65536);
  __hip_bfloat16* wtc_hi = (__hip_bfloat16*)alloc(1114112);      // [4352][512]
  __hip_bfloat16* wtc_lo = (__hip_bfloat16*)alloc(1114112);
  float* basis_f = alloc(3932160);
  float* comp_f = alloc(512);
  float* xw = alloc(33554432);   // fp32 [8192][4096]; overlays below
  float* cnt = alloc(131072);
  float* out1 = alloc(2097152);
  __hip_bfloat16* a2o1_hi = (__hip_bfloat16*)alloc(2097152);     // [8192][512]
  __hip_bfloat16* a2o1_lo = (__hip_bfloat16*)alloc(2097152);
  float* hidden = alloc(2097152);
  int* rowptr = (int*)alloc(8208);
  int* fillc = (int*)alloc(8192);
  int* eidx = (int*)alloc(262144);
  // wt_nat overlays head of xw (consumed by wt_transpose before xw is written)
  float* wt_nat = xw;                                            // [16][512][256]
  // phase B overlays the (consumed) xw region
  float* em = xw;
  __hip_bfloat16* em_hi = (__hip_bfloat16*)(em + 6291456);       // [8192][768]
  __hip_bfloat16* em_lo = (__hip_bfloat16*)(em + 9437184);
  __hip_bfloat16* X_hi = (__hip_bfloat16*)(em + 12582912);
  __hip_bfloat16* X_lo = (__hip_bfloat16*)(em + 15728640);
  float* scores = em + 18874368;                                 // 2,097,152 f
  __hip_bfloat16* a_b16 = (__hip_bfloat16*)(em + 20971520);      // 1,048,576 f
  __hip_bfloat16* att_hi = (__hip_bfloat16*)(em + 22020096);
  __hip_bfloat16* att_lo = (__hip_bfloat16*)(em + 25165824);
  // emT overlays dead em-fp32 head
  __hip_bfloat16* emT_hi = (__hip_bfloat16*)em;
  __hip_bfloat16* emT_lo = (__hip_bfloat16*)(em + 3145728);

  // 0. dtype detect + fused conversion launches
  detect_dtype<<<1, 256, 0, stream>>>((const unsigned short*)d_in[0], flag);
  ConvTable T{};
  long tot = 0;
  int ns = 0;
  auto seg = [&](const void* s, float* d, __hip_bfloat16* hi, __hip_bfloat16* lo,
                 int n, int z) {
    T.seg[ns].src = s; T.seg[ns].dst = d; T.seg[ns].hi = hi; T.seg[ns].lo = lo;
    T.seg[ns].n = n; T.seg[ns].zero = z; ns++; tot += n;
  };
  seg(d_in[0], nullptr, x_hi, x_lo, NN * FF, 0);
  seg(d_in[8], basis_f, nullptr, nullptr, NBASE * FF * HH, 0);
  seg(d_in[9], comp_f, nullptr, nullptr, RR * NBASE, 0);
  seg(d_in[13], b_rel_f, nullptr, nullptr, HH, 0);
  seg(d_in[16], b_att_f, nullptr, nullptr, DD, 0);
  seg(d_in[18], b_lin_f, nullptr, nullptr, HH, 0);
  seg(d_in[19], w_fc_f, nullptr, nullptr, HH * CC, 0);
  seg(d_in[20], b_fc_f, nullptr, nullptr, CC, 0);
  seg(nullptr, biasx, nullptr, nullptr, 4096, 1);
  seg(d_in[11], biasx + 4096, nullptr, nullptr, HH, 0);
  T.count = ns;
  T.total = tot;
  conv_all<<<4096, 256, 0, stream>>>(T, flag);
  TTable TT{};
  long ttot = 0;
  int ts = 0;
  auto tseg = [&](const void* s, __hip_bfloat16* hi, __hip_bfloat16* lo,
                  int R, int C, int ld, int off) {
    TT.seg[ts].src = s; TT.seg[ts].hi = hi; TT.seg[ts].lo = lo;
    TT.seg[ts].R = R; TT.seg[ts].C = C; TT.seg[ts].ld = ld; TT.seg[ts].off = off;
    ts++; ttot += (long)R * C;
  };
  tseg(d_in[15], watt_hi, watt_lo, DD, DD, DD, 0);               // w_att^T
  tseg(d_in[17], wlin_hi, wlin_lo, DD, HH, DD, 0);               // w_lin^T
  tseg(d_in[10], wtc_hi + 4096 * 512, wtc_lo + 4096 * 512, FF, HH, FF, 0);  // root1^T
  tseg(d_in[12], wrr_hi, wrr_lo, HH, HH, 512, 0);                // w_rel^T
  tseg(d_in[14], wrr_hi, wrr_lo, HH, HH, 512, 256);              // w_root^T
  TT.count = ts;
  TT.total = ttot;
  split_t_all<<<2048, 256, 0, stream>>>(TT, flag);

  // 1. Wt: coalesced GEMM into natural layout, then LDS-tiled transpose + split
  wt_gemm<<<131072 / 256, 256, 0, stream>>>(basis_f, comp_f, wt_nat);
  wt_transpose<<<dim3(8, 16, 16), 256, 0, stream>>>(wt_nat, wtc_hi, wtc_lo);
  // 2. merged xw|out1 = x @ [W | root1] + [0 | bias1]  (cols>=4096 -> out1)
  mfma_dual<<<dim3(34, 64, 1), 256, 0, stream>>>(
      x_hi, x_lo, wtc_hi, wtc_lo, biasx, xw, out1, nullptr, nullptr, FF, 4096,
      0, 0, 0, FLAG_BIAS | FLAG_TAILOUT);
  // 3. CSR build
  hipMemsetAsync(cnt, 0, 131072 * sizeof(float), stream);
  count_edges<<<EE / 256, 256, 0, stream>>>(ei, et, cnt);
  scan_rowptr<<<1, 256, 0, stream>>>(cnt, rowptr, fillc);
  edge_fill<<<EE / 256, 256, 0, stream>>>(ei, et, rowptr, fillc, eidx);
  // 4/5. aggregations (gather); emit [agg2|out1] hi/lo as out2-GEMM A operand
  rgcn_gather<<<NN, 256, 0, stream>>>(rowptr, eidx, cnt, xw, out1, a2o1_hi, a2o1_lo);
  graphconv_gather<<<NN, 256, 0, stream>>>(rowptr, eidx, out1, a2o1_hi, a2o1_lo);
  // 6. em cols 0:512 = x (split); cols 512:768 = out2 via split-MFMA
  copy_xsplit<<<(NN * FF) / 256, 256, 0, stream>>>(x_hi, x_lo, em_hi, em_lo);
  mfma_dual<<<dim3(2, 64, 1), 256, 0, stream>>>(
      a2o1_hi, a2o1_lo, wrr_hi, wrr_lo, b_rel_f, nullptr, nullptr,
      em_hi + 512, em_lo + 512, 512, DD, 0, 0, 0, FLAG_BIAS | FLAG_SPLITOUT);
  // 6b. emT (for att B-operand)
  transpose_b16<<<dim3(24, 8, 32), 256, 0, stream>>>(em_hi, emT_hi);
  transpose_b16<<<dim3(24, 8, 32), 256, 0, stream>>>(em_lo, emT_lo);
  // 7. X = emotions @ w_att + b_att -> split out
  mfma_dual<<<dim3(6, 64, 1), 256, 0, stream>>>(
      em_hi, em_lo, watt_hi, watt_lo, b_att_f, nullptr, nullptr, X_hi, X_lo, DD, DD,
      0, 0, 0, FLAG_BIAS | FLAG_SPLITOUT);
  // 8. scores = tanh(X_b . em_b^T) (batched, fp32 out)
  mfma_dual<<<dim3(2, 2, BB), 256, 0, stream>>>(
      X_hi, X_lo, em_hi, em_lo, nullptr, scores, nullptr, nullptr, nullptr, DD, LL,
      (long)LL * DD, (long)LL * DD, (long)LL * LL, FLAG_TANH);
  // 9. softmax over s -> bf16 attention weights
  softmax256<<<BB * LL, 256, 0, stream>>>(scores, a_b16);
  // 10. att_b = a_b @ em_b (batched, split out)
  mfma_dual<<<dim3(6, 2, BB), 256, 0, stream>>>(
      a_b16, nullptr, emT_hi, emT_lo, nullptr, nullptr, nullptr, att_hi, att_lo, LL, DD,
      (long)LL * LL, (long)LL * DD, (long)LL * DD, FLAG_SPLITOUT);
  // 11. hidden = relu(att @ w_lin + b_lin)
  mfma_dual<<<dim3(2, 64, 1), 256, 0, stream>>>(
      att_hi, att_lo, wlin_hi, wlin_lo, b_lin_f, hidden, nullptr, nullptr, nullptr,
      DD, HH, 0, 0, 0, FLAG_BIAS | FLAG_RELU);
  // 12. logits + log_softmax over batch axis
  logits_lsm<<<LL, 256, 0, stream>>>(hidden, w_fc_f, b_fc_f, d_out, flag);
}

// Round 12
// 634.350 us; speedup vs baseline: 1.2319x; 1.0292x over previous
//
#include <hip/hip_runtime.h>
#include <hip/hip_bf16.h>

// Problem constants (fixed by setup_inputs)
#define NN 8192
#define FF 512
#define HH 256
#define RR 16
#define BB 32
#define LL 256
#define CC 7
#define EE 262144
#define NBASE 30
#define DD 768

constexpr int FLAG_BIAS = 1, FLAG_RELU = 4, FLAG_TANH = 8,
              FLAG_SPLITOUT = 16, FLAG_TAILOUT = 32;

typedef __attribute__((ext_vector_type(8))) short bf16x8;
typedef __attribute__((ext_vector_type(4))) float f32x4;

// ------------- dtype detection (robustness) -----------------------------------
__global__ __launch_bounds__(256) void detect_dtype(const unsigned short* __restrict__ xs,
                                                    int* __restrict__ flag) {
  __shared__ int red[256];
  int cnt = 0;
  for (int i = threadIdx.x * 2; i < 8192; i += 512) {
    unsigned short u = xs[i];
    int e = (u >> 7) & 0xFF;
    if (e >= 0xC0) cnt++;
  }
  red[threadIdx.x] = cnt;
  __syncthreads();
  for (int s = 128; s > 0; s >>= 1) {
    if (threadIdx.x < s) red[threadIdx.x] += red[threadIdx.x + s];
    __syncthreads();
  }
  if (threadIdx.x == 0) flag[0] = (red[0] > 16) ? 1 : 0;  // 1 = fp32 data
}

// ------------- fused conversion: all small tensors in one launch ---------------
struct ConvSeg {
  const void* src;
  float* dst;
  __hip_bfloat16* hi;
  __hip_bfloat16* lo;
  int n;
  int zero;
};
struct ConvTable {
  ConvSeg seg[12];
  int count;
  long total;
};

__global__ __launch_bounds__(256) void conv_all(ConvTable t, const int* __restrict__ flag) {
  const int fp32 = flag[0];
  for (long i = (long)blockIdx.x * 256 + threadIdx.x; i < t.total;
       i += (long)gridDim.x * 256) {
    long off = i;
    int s = 0;
    while (off >= t.seg[s].n) { off -= t.seg[s].n; s++; }
    const ConvSeg& sg = t.seg[s];
    float v = 0.f;
    if (!sg.zero)
      v = fp32 ? ((const float*)sg.src)[off]
               : __bfloat162float(((const __hip_bfloat16*)sg.src)[off]);
    if (sg.dst) sg.dst[off] = v;
    if (sg.hi) {
      __hip_bfloat16 h = __float2bfloat16(v);
      sg.hi[off] = h;
      sg.lo[off] = __float2bfloat16(v - __bfloat162float(h));
    }
  }
}

// ------------- fused transpose+split for all weight matrices -------------------
struct TSeg {
  const void* src;
  __hip_bfloat16* hi;
  __hip_bfloat16* lo;
  int R, C, ld, off;
};
struct TTable {
  TSeg seg[6];
  int count;
  long total;
};

__global__ __launch_bounds__(256) void split_t_all(TTable t, const int* __restrict__ flag) {
  const int fp32 = flag[0];
  for (long i = (long)blockIdx.x * 256 + threadIdx.x; i < t.total;
       i += (long)gridDim.x * 256) {
    long off = i;
    int s = 0;
    while (off >= (long)t.seg[s].R * t.seg[s].C) { off -= (long)t.seg[s].R * t.seg[s].C; s++; }
    const TSeg& sg = t.seg[s];
    int r = (int)(off % sg.R), c = (int)(off / sg.R);
    float v = fp32 ? ((const float*)sg.src)[(long)r * sg.C + c]
                   : __bfloat162float(((const __hip_bfloat16*)sg.src)[(long)r * sg.C + c]);
    __hip_bfloat16 h = __float2bfloat16(v);
    long d = (long)c * sg.ld + sg.off + r;
    sg.hi[d] = h;
    sg.lo[d] = __float2bfloat16(v - __bfloat162float(h));
  }
}

// copy x_hi/x_lo [8192][512] into em_hi/lo [8192][768] cols 0:512
__global__ __launch_bounds__(256) void copy_xsplit(
    const __hip_bfloat16* __restrict__ xh, const __hip_bfloat16* __restrict__ xl,
    __hip_bfloat16* __restrict__ eh, __hip_bfloat16* __restrict__ el) {
  int idx = blockIdx.x * 256 + threadIdx.x;  // 8192*512
  int n = idx >> 9, f = idx & 511;
  long d = (long)n * DD + f;
  eh[d] = xh[idx];
  el[d] = xl[idx];
}

// emw [32][256][256] -> emwT [32][256][256] transposed per batch;
// z<32 handles hi, z>=32 handles lo.
__global__ __launch_bounds__(256) void transpose_emw(
    const __hip_bfloat16* __restrict__ hi_src, const __hip_bfloat16* __restrict__ lo_src,
    __hip_bfloat16* __restrict__ hi_dst, __hip_bfloat16* __restrict__ lo_dst) {
  __shared__ __hip_bfloat16 t[32][33];
  const int zz = blockIdx.z;
  const __hip_bfloat16* src = (zz < 32) ? hi_src : lo_src;
  __hip_bfloat16* dst = (zz < 32) ? hi_dst : lo_dst;
  const long b = zz & 31;
  const int d0 = blockIdx.x * 32, s0 = blockIdx.y * 32;
  const int c = threadIdx.x & 31, rw = threadIdx.x >> 5;
  const __hip_bfloat16* sp = src + b * (LL * 256);
  __hip_bfloat16* dp = dst + b * (LL * 256);
#pragma unroll
  for (int i = 0; i < 4; ++i)
    t[rw + i * 8][c] = sp[(long)(s0 + rw + i * 8) * 256 + d0 + c];
  __syncthreads();
#pragma unroll
  for (int i = 0; i < 4; ++i)
    dp[(long)(d0 + rw + i * 8) * 256 + s0 + c] = t[c][rw + i * 8];
}

// ---- wt_nat[r][f][h] = sum_b comp[r,b]*basis[b][f][h] ------------------------
__global__ __launch_bounds__(256) void wt_gemm(
    const float* __restrict__ basis, const float* __restrict__ comp,
    float* __restrict__ wt_nat) {
  __shared__ float cs[RR * NBASE];
  int tid = threadIdx.x;
  for (int i = tid; i < RR * NBASE; i += 256) cs[i] = comp[i];
  __syncthreads();
  long col = (long)blockIdx.x * 256 + tid;
  float acc[RR] = {};
  for (int b = 0; b < NBASE; ++b) {
    float v = basis[(long)b * 131072 + col];
#pragma unroll
    for (int r = 0; r < RR; ++r) acc[r] += cs[r * NBASE + b] * v;
  }
#pragma unroll
  for (int r = 0; r < RR; ++r) wt_nat[(long)r * 131072 + col] = acc[r];
}

// ---- wt_nat [16][512][256] (r,f,h) -> wtc[(r*256+h)][512] hi/lo --------------
__global__ __launch_bounds__(256) void wt_transpose(
    const float* __restrict__ wt_nat,
    __hip_bfloat16* __restrict__ hi, __hip_bfloat16* __restrict__ lo) {
  __shared__ float t[32][33];
  const int r = blockIdx.z;
  const int f0 = blockIdx.y * 32, h0 = blockIdx.x * 32;
  const int c = threadIdx.x & 31, rw = threadIdx.x >> 5;
  const float* src = wt_nat + ((long)r * 512 + f0) * 256 + h0;
#pragma unroll
  for (int i = 0; i < 4; ++i)
    t[rw + i * 8][c] = src[(long)(rw + i * 8) * 256 + c];
  __syncthreads();
#pragma unroll
  for (int i = 0; i < 4; ++i) {
    int hh = rw + i * 8;
    float v = t[c][hh];
    long orow = (long)(r * 256 + h0 + hh) * 512 + f0 + c;
    __hip_bfloat16 hv = __float2bfloat16(v);
    hi[orow] = hv;
    lo[orow] = __float2bfloat16(v - __bfloat162float(hv));
  }
}

// ---------------- fused dual-precision MFMA GEMM ------------------------------
// One K-pass: acc += Ahi@Bhi + Ahi@Blo (+ Alo@Bhi). 128x128 tile, BK=32,
// 4 waves, 16x16x32 bf16 MFMA, global_load_lds w=16.
// __launch_bounds__(256,3): cap unified VGPR to keep 3 blocks/CU.
__device__ __forceinline__ void gload_lds16(const void* g, void* l) {
  __builtin_amdgcn_global_load_lds(
      (const __attribute__((address_space(1))) unsigned int*)g,
      (__attribute__((address_space(3))) unsigned int*)l, 16, 0, 0);
}

__global__ __launch_bounds__(256, 3) void mfma_dual(
    const __hip_bfloat16* __restrict__ A, const __hip_bfloat16* __restrict__ Alo,
    const __hip_bfloat16* __restrict__ Bt, const __hip_bfloat16* __restrict__ Btlo,
    const float* __restrict__ bias, float* __restrict__ C, float* __restrict__ Ct,
    __hip_bfloat16* __restrict__ Chi, __hip_bfloat16* __restrict__ Clo,
    int K, int ldc, long sA, long sB, long sC, int flags) {
  __shared__ __hip_bfloat16 Ah[128 * 32];
  __shared__ __hip_bfloat16 Bh[128 * 32];
  __shared__ __hip_bfloat16 Al[128 * 32];
  __shared__ __hip_bfloat16 Bl[128 * 32];
  const int tid = threadIdx.x;
  const int w = tid >> 6, lane = tid & 63;
  const long z = blockIdx.z;
  const long row0 = (long)blockIdx.y * 128, col0 = (long)blockIdx.x * 128;
  const int wm = w & 1, wn = w >> 1;
  const int srow0 = (w * 128 + lane) >> 2;
  const int srow1 = (w * 128 + 64 + lane) >> 2;
  const int kch = (lane & 3) * 8;
  const int fr = lane & 15, q = lane >> 4;
  const bool hasAlo = (Alo != nullptr);
  const __hip_bfloat16* Az = A + z * sA;
  const __hip_bfloat16* Alz = hasAlo ? (Alo + z * sA) : nullptr;
  const __hip_bfloat16* Bz = Bt + z * sB;
  const __hip_bfloat16* Blz = Btlo + z * sB;
  const long aoff0 = (row0 + srow0) * K + kch, aoff1 = (row0 + srow1) * K + kch;
  const long boff0 = (col0 + srow0) * K + kch, boff1 = (col0 + srow1) * K + kch;
  f32x4 acc[4][4] = {};
  for (int k0 = 0; k0 < K; k0 += 32) {
    gload_lds16(Az + aoff0 + k0, Ah + w * 1024);
    gload_lds16(Az + aoff1 + k0, Ah + w * 1024 + 512);
    gload_lds16(Bz + boff0 + k0, Bh + w * 1024);
    gload_lds16(Bz + boff1 + k0, Bh + w * 1024 + 512);
    gload_lds16(Blz + boff0 + k0, Bl + w * 1024);
    gload_lds16(Blz + boff1 + k0, Bl + w * 1024 + 512);
    if (hasAlo) {
      gload_lds16(Alz + aoff0 + k0, Al + w * 1024);
      gload_lds16(Alz + aoff1 + k0, Al + w * 1024 + 512);
    }
    __syncthreads();
    bf16x8 ah[4], bh[4], bl[4];
#pragma unroll
    for (int i = 0; i < 4; ++i) {
      ah[i] = *(const bf16x8*)&Ah[(wm * 64 + i * 16 + fr) * 32 + q * 8];
      bh[i] = *(const bf16x8*)&Bh[(wn * 64 + i * 16 + fr) * 32 + q * 8];
      bl[i] = *(const bf16x8*)&Bl[(wn * 64 + i * 16 + fr) * 32 + q * 8];
    }
#pragma unroll
    for (int i = 0; i < 4; ++i)
#pragma unroll
      for (int j = 0; j < 4; ++j) {
        acc[i][j] = __builtin_amdgcn_mfma_f32_16x16x32_bf16(ah[i], bh[j], acc[i][j], 0, 0, 0);
        acc[i][j] = __builtin_amdgcn_mfma_f32_16x16x32_bf16(ah[i], bl[j], acc[i][j], 0, 0, 0);
      }
    if (hasAlo) {
      bf16x8 al[4];
#pragma unroll
      for (int i = 0; i < 4; ++i)
        al[i] = *(const bf16x8*)&Al[(wm * 64 + i * 16 + fr) * 32 + q * 8];
#pragma unroll
      for (int i = 0; i < 4; ++i)
#pragma unroll
        for (int j = 0; j < 4; ++j)
          acc[i][j] = __builtin_amdgcn_mfma_f32_16x16x32_bf16(al[i], bh[j], acc[i][j], 0, 0, 0);
    }
    __syncthreads();
  }
  const int cr = (lane >> 4) * 4, cc = lane & 15;
  float* Cz = C ? (C + z * sC) : nullptr;
  __hip_bfloat16* Chz = Chi ? (Chi + z * sC) : nullptr;
  __hip_bfloat16* Clz = Clo ? (Clo + z * sC) : nullptr;
#pragma unroll
  for (int i = 0; i < 4; ++i) {
    long rbase = row0 + wm * 64 + i * 16 + cr;
#pragma unroll
    for (int j = 0; j < 4; ++j) {
      long col = col0 + wn * 64 + j * 16 + cc;
      float bv = (flags & FLAG_BIAS) ? bias[col] : 0.f;
#pragma unroll
      for (int r = 0; r < 4; ++r) {
        float v = acc[i][j][r] + bv;
        if (flags & FLAG_RELU) v = fmaxf(v, 0.f);
        if (flags & FLAG_TANH) v = tanhf(v);
        if (flags & FLAG_SPLITOUT) {
          long off = (rbase + r) * ldc + col;
          __hip_bfloat16 hv = __float2bfloat16(v);
          Chz[off] = hv;
          Clz[off] = __float2bfloat16(v - __bfloat162float(hv));
        } else if ((flags & FLAG_TAILOUT) && col >= 4096) {
          Ct[(rbase + r) * 256 + (col - 4096)] = v;
        } else {
          Cz[(rbase + r) * ldc + col] = v;
        }
      }
    }
  }
}

// ---------------- edge kernels: CSR build + gathers ----------------------------
__global__ __launch_bounds__(256) void count_edges(
    const int* __restrict__ ei, const int* __restrict__ et, float* __restrict__ cnt) {
  int e = blockIdx.x * 256 + threadIdx.x;
  if (e < EE) atomicAdd(&cnt[ei[EE + e] * RR + et[e]], 1.0f);
}

__global__ __launch_bounds__(256) void scan_rowptr(
    const float* __restrict__ cntf, int* __restrict__ rowptr, int* __restrict__ fill) {
  __shared__ int part[256];
  int tid = threadIdx.x;
  int base = tid * 32;
  int local[32];
  int s = 0;
  for (int i = 0; i < 32; ++i) {
    local[i] = s;
    const float* c = &cntf[(base + i) * RR];
    int d = 0;
#pragma unroll
    for (int r = 0; r < RR; ++r) d += (int)c[r];
    s += d;
  }
  part[tid] = s;
  __syncthreads();
  for (int off = 1; off < 256; off <<= 1) {
    int v = (tid >= off) ? part[tid - off] : 0;
    __syncthreads();
    part[tid] += v;
    __syncthreads();
  }
  int prev = (tid == 0) ? 0 : part[tid - 1];
  for (int i = 0; i < 32; ++i) rowptr[base + i] = prev + local[i];
  if (tid == 255) rowptr[8192] = part[255];
  for (int i = tid; i < 8192; i += 256) fill[i] = 0;
}

__global__ __launch_bounds__(256) void edge_fill(
    const int* __restrict__ ei, const int* __restrict__ et,
    const int* __restrict__ rowptr, int* __restrict__ fill, int* __restrict__ eidx) {
  int e = blockIdx.x * 256 + threadIdx.x;
  if (e < EE) {
    int dst = ei[EE + e];
    int pos = rowptr[dst] + atomicAdd(&fill[dst], 1);
    eidx[pos] = ei[e] | (et[e] << 16);
  }
}

// out1 += mean-agg; also emit split into a2o1 cols 256:512 (A of out2 GEMM)
__global__ __launch_bounds__(256) void rgcn_gather(
    const int* __restrict__ rowptr, const int* __restrict__ eidx,
    const float* __restrict__ cntf, const float* __restrict__ xw,
    float* __restrict__ out1, __hip_bfloat16* __restrict__ a2o1_hi,
    __hip_bfloat16* __restrict__ a2o1_lo) {
  const int dst = blockIdx.x;
  const int h = threadIdx.x;
  __shared__ float inv[RR];
  __shared__ int se[256];
  if (h < RR) inv[h] = 1.0f / fmaxf(cntf[dst * RR + h], 1.0f);
  const int beg = rowptr[dst], end = rowptr[dst + 1];
  float acc = 0.f;
  for (int c0 = beg; c0 < end; c0 += 256) {
    int n = min(256, end - c0);
    __syncthreads();
    if (h < n) se[h] = eidx[c0 + h];
    __syncthreads();
    for (int i = 0; i < n; ++i) {
      int pk = se[i];
      int src = pk & 0xFFFF, r = pk >> 16;
      acc += xw[((long)src << 12) + (r << 8) + h] * inv[r];
    }
  }
  float tot = out1[((long)dst << 8) + h] + acc;
  out1[((long)dst << 8) + h] = tot;
  __hip_bfloat16 hv = __float2bfloat16(tot);
  long d = (long)dst * 512 + 256 + h;
  a2o1_hi[d] = hv;
  a2o1_lo[d] = __float2bfloat16(tot - __bfloat162float(hv));
}

// a2o1 cols 0:256 = sum_{src->dst} out1[src] (split)
__global__ __launch_bounds__(256) void graphconv_gather(
    const int* __restrict__ rowptr, const int* __restrict__ eidx,
    const float* __restrict__ out1, __hip_bfloat16* __restrict__ a2o1_hi,
    __hip_bfloat16* __restrict__ a2o1_lo) {
  const int dst = blockIdx.x;
  const int h = threadIdx.x;
  __shared__ int se[256];
  const int beg = rowptr[dst], end = rowptr[dst + 1];
  float acc = 0.f;
  for (int c0 = beg; c0 < end; c0 += 256) {
    int n = min(256, end - c0);
    __syncthreads();
    if (h < n) se[h] = eidx[c0 + h];
    __syncthreads();
    for (int i = 0; i < n; ++i)
      acc += out1[((long)(se[i] & 0xFFFF) << 8) + h];
  }
  __hip_bfloat16 hv = __float2bfloat16(acc);
  long d = (long)dst * 512 + h;
  a2o1_hi[d] = hv;
  a2o1_lo[d] = __float2bfloat16(acc - __bfloat162float(hv));
}

// ---------------- softmax over last dim (256), bf16 weights out ---------------
__global__ __launch_bounds__(256) void softmax256(const float* __restrict__ S,
                                                  __hip_bfloat16* __restrict__ Ab) {
  __shared__ float red[256];
  long row = blockIdx.x;
  const float* p = S + row * 256;
  int t = threadIdx.x;
  float v = p[t];
  red[t] = v;
  __syncthreads();
  for (int s = 128; s > 0; s >>= 1) {
    if (t < s) red[t] = fmaxf(red[t], red[t + s]);
    __syncthreads();
  }
  float m = red[0];
  __syncthreads();
  float e = __expf(v - m);
  red[t] = e;
  __syncthreads();
  for (int s = 128; s > 0; s >>= 1) {
    if (t < s) red[t] += red[t + s];
    __syncthreads();
  }
  Ab[row * 256 + t] = __float2bfloat16(e / red[0]);
}

// ---------------- logits + log_softmax over batch axis (faithful dim=1) -------
__global__ __launch_bounds__(256) void logits_lsm(
    const float* __restrict__ hidden, const float* __restrict__ w_fc,
    const float* __restrict__ b_fc, void* __restrict__ out_v,
    const int* __restrict__ flag) {
  __shared__ float wf[256 * 7];
  __shared__ float lg[224];
  __shared__ float corr[7];
  int t = blockIdx.x;
  int tid = threadIdx.x;
  for (int i = tid; i < 256 * 7; i += 256) wf[i] = w_fc[i];
  __syncthreads();
  if (tid < 224) {
    int b = tid / 7, c = tid % 7;
    const float* hr = hidden + ((long)((b << 8) + t) << 8);
    float s = b_fc[c];
    for (int k = 0; k < 256; ++k) s += hr[k] * wf[k * 7 + c];
    lg[tid] = s;
  }
  __syncthreads();
  if (tid < 7) {
    float m = -1e30f;
    for (int b = 0; b < BB; ++b) m = fmaxf(m, lg[b * 7 + tid]);
    float sum = 0.f;
    for (int b = 0; b < BB; ++b) sum += __expf(lg[b * 7 + tid] - m);
    corr[tid] = m + logf(sum);
  }
  __syncthreads();
  if (tid < 224) {
    float v = lg[tid] - corr[tid % 7];
    if (flag[0]) ((float*)out_v)[t * 224 + tid] = v;
    else ((__hip_bfloat16*)out_v)[t * 224 + tid] = __float2bfloat16(v);
  }
}

extern "C" void kernel_launch(void* const* d_in, const int* in_sizes, int n_in,
                              void* d_out, int out_size, void* d_ws, size_t ws_size,
                              hipStream_t stream) {
  const int* ei = (const int*)d_in[1];
  const int* et = (const int*)d_in[3];

  float* ws = (float*)d_ws;
  int* flag = (int*)d_ws;
  float* p = ws + 16;
  auto alloc = [&](long nf) { float* r = p; p += nf; return r; };
  float* w_fc_f = alloc(1792);
  float* b_rel_f = alloc(256);
  float* biasx = alloc(4352);                                    // [0..4095]=0, tail=bias1
  float* b_att_f = alloc(768);
  float* b_lin_f = alloc(256);
  float* b_fc_f = alloc(16);
  __hip_bfloat16* wlin_hi = (__hip_bfloat16*)alloc(98304);       // [256][768]
  __hip_bfloat16* wlin_lo = (__hip_bfloat16*)alloc(98304);
  __hip_bfloat16* x_hi = (__hip_bfloat16*)alloc(2097152);        // [8192][512]
  __hip_bfloat16* x_lo = (__hip_bfloat16*)alloc(2097152);
  __hip_bfloat16* watt_hi = (__hip_bfloat16*)alloc(294912);      // [768][768]
  __hip_bfloat16* watt_lo = (__hip_bfloat16*)alloc(294912);
  __hip_bfloat16* wrr_hi = (__hip_bfloat16*)alloc(65536);        // [256][512] = [w_rel;w_root]^T
  __hip_bfloat16* wrr_lo = (__hip_bfloat16*)alloc(65536);
  __hip_bfloat16* wtc_hi = (__hip_bfloat16*)alloc(1114112);      // [4352][512]
  __hip_bfloat16* wtc_lo = (__hip_bfloat16*)alloc(1114112);
  float* basis_f = alloc(3932160);
  float* comp_f = alloc(512);
  float* xw = alloc(33554432);   // fp32 [8192][4096]; overlays below
  float* cnt = alloc(131072);
  float* out1 = alloc(2097152);
  __hip_bfloat16* a2o1_hi = (__hip_bfloat16*)alloc(2097152);     // [8192][512]
  __hip_bfloat16* a2o1_lo = (__hip_bfloat16*)alloc(2097152);
  float* hidden = alloc(2097152);
  int* rowptr = (int*)alloc(8208);
  int* fillc = (int*)alloc(8192);
  int* eidx = (int*)alloc(262144);
  // wt_nat overlays head of xw (consumed by wt_transpose before xw is written)
  float* wt_nat = xw;                                            // [16][512][256]
  // phase B overlays the (consumed) xw region
  float* em = xw;
  __hip_bfloat16* emw_hi = (__hip_bfloat16*)em;                  // [8192][256]
  __hip_bfloat16* emw_lo = (__hip_bfloat16*)(em + 1048576);
  __hip_bfloat16* emwT_hi = (__hip_bfloat16*)(em + 2097152);     // [32][256][256]
  __hip_bfloat16* emwT_lo = (__hip_bfloat16*)(em + 3145728);
  __hip_bfloat16* em_hi = (__hip_bfloat16*)(em + 6291456);       // [8192][768]
  __hip_bfloat16* em_lo = (__hip_bfloat16*)(em + 9437184);
  __hip_bfloat16* X_hi = (__hip_bfloat16*)(em + 12582912);
  __hip_bfloat16* X_lo = (__hip_bfloat16*)(em + 15728640);
  float* scores = em + 18874368;                                 // 2,097,152 f
  __hip_bfloat16* a_b16 = (__hip_bfloat16*)(em + 20971520);      // 1,048,576 f

  // 0. dtype detect + fused conversion launches
  detect_dtype<<<1, 256, 0, stream>>>((const unsigned short*)d_in[0], flag);
  ConvTable T{};
  long tot = 0;
  int ns = 0;
  auto seg = [&](const void* s, float* d, __hip_bfloat16* hi, __hip_bfloat16* lo,
                 int n, int z) {
    T.seg[ns].src = s; T.seg[ns].dst = d; T.seg[ns].hi = hi; T.seg[ns].lo = lo;
    T.seg[ns].n = n; T.seg[ns].zero = z; ns++; tot += n;
  };
  seg(d_in[0], nullptr, x_hi, x_lo, NN * FF, 0);
  seg(d_in[8], basis_f, nullptr, nullptr, NBASE * FF * HH, 0);
  seg(d_in[9], comp_f, nullptr, nullptr, RR * NBASE, 0);
  seg(d_in[13], b_rel_f, nullptr, nullptr, HH, 0);
  seg(d_in[16], b_att_f, nullptr, nullptr, DD, 0);
  seg(d_in[18], b_lin_f, nullptr, nullptr, HH, 0);
  seg(d_in[19], w_fc_f, nullptr, nullptr, HH * CC, 0);
  seg(d_in[20], b_fc_f, nullptr, nullptr, CC, 0);
  seg(nullptr, biasx, nullptr, nullptr, 4096, 1);
  seg(d_in[11], biasx + 4096, nullptr, nullptr, HH, 0);
  T.count = ns;
  T.total = tot;
  conv_all<<<4096, 256, 0, stream>>>(T, flag);
  TTable TT{};
  long ttot = 0;
  int ts = 0;
  auto tseg = [&](const void* s, __hip_bfloat16* hi, __hip_bfloat16* lo,
                  int R, int C, int ld, int off) {
    TT.seg[ts].src = s; TT.seg[ts].hi = hi; TT.seg[ts].lo = lo;
    TT.seg[ts].R = R; TT.seg[ts].C = C; TT.seg[ts].ld = ld; TT.seg[ts].off = off;
    ts++; ttot += (long)R * C;
  };
  tseg(d_in[15], watt_hi, watt_lo, DD, DD, DD, 0);               // w_att^T
  tseg(d_in[17], wlin_hi, wlin_lo, DD, HH, DD, 0);               // w_lin^T
  tseg(d_in[10], wtc_hi + 4096 * 512, wtc_lo + 4096 * 512, FF, HH, FF, 0);  // root1^T
  tseg(d_in[12], wrr_hi, wrr_lo, HH, HH, 512, 0);                // w_rel^T
  tseg(d_in[14], wrr_hi, wrr_lo, HH, HH, 512, 256);              // w_root^T
  TT.count = ts;
  TT.total = ttot;
  split_t_all<<<2048, 256, 0, stream>>>(TT, flag);

  // 1. Wt: coalesced GEMM into natural layout, then LDS-tiled transpose + split
  wt_gemm<<<131072 / 256, 256, 0, stream>>>(basis_f, comp_f, wt_nat);
  wt_transpose<<<dim3(8, 16, 16), 256, 0, stream>>>(wt_nat, wtc_hi, wtc_lo);
  // 2. merged xw|out1 = x @ [W | root1] + [0 | bias1]  (cols>=4096 -> out1)
  mfma_dual<<<dim3(34, 64, 1), 256, 0, stream>>>(
      x_hi, x_lo, wtc_hi, wtc_lo, biasx, xw, out1, nullptr, nullptr, FF, 4096,
      0, 0, 0, FLAG_BIAS | FLAG_TAILOUT);
  // 3. CSR build
  hipMemsetAsync(cnt, 0, 131072 * sizeof(float), stream);
  count_edges<<<EE / 256, 256, 0, stream>>>(ei, et, cnt);
  scan_rowptr<<<1, 256, 0, stream>>>(cnt, rowptr, fillc);
  edge_fill<<<EE / 256, 256, 0, stream>>>(ei, et, rowptr, fillc, eidx);
  // 4/5. aggregations (gather); emit [agg2|out1] hi/lo as out2-GEMM A operand
  rgcn_gather<<<NN, 256, 0, stream>>>(rowptr, eidx, cnt, xw, out1, a2o1_hi, a2o1_lo);
  graphconv_gather<<<NN, 256, 0, stream>>>(rowptr, eidx, out1, a2o1_hi, a2o1_lo);
  // 6. em cols 0:512 = x (split); cols 512:768 = out2 via split-MFMA
  copy_xsplit<<<(NN * FF) / 256, 256, 0, stream>>>(x_hi, x_lo, em_hi, em_lo);
  mfma_dual<<<dim3(2, 64, 1), 256, 0, stream>>>(
      a2o1_hi, a2o1_lo, wrr_hi, wrr_lo, b_rel_f, nullptr, nullptr,
      em_hi + 512, em_lo + 512, 512, DD, 0, 0, 0, FLAG_BIAS | FLAG_SPLITOUT);
  // 6b. emw = em @ w_lin (split out; hidden = relu(a@emw + b_lin) later)
  mfma_dual<<<dim3(2, 64, 1), 256, 0, stream>>>(
      em_hi, em_lo, wlin_hi, wlin_lo, nullptr, nullptr, nullptr, emw_hi, emw_lo,
      DD, HH, 0, 0, 0, FLAG_SPLITOUT);
  transpose_emw<<<dim3(8, 8, 64), 256, 0, stream>>>(emw_hi, emw_lo, emwT_hi, emwT_lo);
  // 7. X = emotions @ w_att + b_att -> split out
  mfma_dual<<<dim3(6, 64, 1), 256, 0, stream>>>(
      em_hi, em_lo, watt_hi, watt_lo, b_att_f, nullptr, nullptr, X_hi, X_lo, DD, DD,
      0, 0, 0, FLAG_BIAS | FLAG_SPLITOUT);
  // 8. scores = tanh(X_b . em_b^T) (batched, fp32 out)
  mfma_dual<<<dim3(2, 2, BB), 256, 0, stream>>>(
      X_hi, X_lo, em_hi, em_lo, nullptr, scores, nullptr, nullptr, nullptr, DD, LL,
      (long)LL * DD, (long)LL * DD, (long)LL * LL, FLAG_TANH);
  // 9. softmax over s -> bf16 attention weights
  softmax256<<<BB * LL, 256, 0, stream>>>(scores, a_b16);
  // 10. hidden = relu(a @ emwT + b_lin)  [= relu((a@em)@w_lin + b_lin)]
  mfma_dual<<<dim3(2, 2, BB), 256, 0, stream>>>(
      a_b16, nullptr, emwT_hi, emwT_lo, b_lin_f, hidden, nullptr, nullptr, nullptr,
      LL, HH, (long)LL * LL, (long)LL * HH, (long)LL * HH, FLAG_BIAS | FLAG_RELU);
  // 11. logits + log_softmax over batch axis
  logits_lsm<<<LL, 256, 0, stream>>>(hidden, w_fc_f, b_fc_f, d_out, flag);
}

// Round 13
// 622.678 us; speedup vs baseline: 1.2550x; 1.0187x over previous
//
#include <hip/hip_runtime.h>
#include <hip/hip_bf16.h>

// Problem constants (fixed by setup_inputs)
#define NN 8192
#define FF 512
#define HH 256
#define RR 16
#define BB 32
#define LL 256
#define CC 7
#define EE 262144
#define NBASE 30
#define DD 768

constexpr int FLAG_BIAS = 1, FLAG_RELU = 4, FLAG_TANH = 8,
              FLAG_SPLITOUT = 16, FLAG_TAILOUT = 32, FLAG_TAIL2 = 64;

typedef __attribute__((ext_vector_type(8))) short bf16x8;
typedef __attribute__((ext_vector_type(4))) float f32x4;

// ------------- dtype detection (robustness) -----------------------------------
__global__ __launch_bounds__(256) void detect_dtype(const unsigned short* __restrict__ xs,
                                                    int* __restrict__ flag) {
  __shared__ int red[256];
  int cnt = 0;
  for (int i = threadIdx.x * 2; i < 8192; i += 512) {
    unsigned short u = xs[i];
    int e = (u >> 7) & 0xFF;
    if (e >= 0xC0) cnt++;
  }
  red[threadIdx.x] = cnt;
  __syncthreads();
  for (int s = 128; s > 0; s >>= 1) {
    if (threadIdx.x < s) red[threadIdx.x] += red[threadIdx.x + s];
    __syncthreads();
  }
  if (threadIdx.x == 0) flag[0] = (red[0] > 16) ? 1 : 0;  // 1 = fp32 data
}

// ------------- unified prep: conversions + transposed splits, one launch -------
struct PSeg {
  const void* src;
  float* dst;
  __hip_bfloat16* hi;
  __hip_bfloat16* lo;
  __hip_bfloat16* hi2;   // optional second (strided) split dest (x -> em cols)
  __hip_bfloat16* lo2;
  long n;                // R*C elements
  int R, C, ld, off;     // transpose geometry (type==1)
  int type;              // 0 = linear, 1 = transpose-split
  int zero;
};
struct PTable {
  PSeg seg[16];
  int count;
  long total;
};

__global__ __launch_bounds__(256) void prep_all(PTable t, const int* __restrict__ flag) {
  const int fp32 = flag[0];
  for (long i = (long)blockIdx.x * 256 + threadIdx.x; i < t.total;
       i += (long)gridDim.x * 256) {
    long off = i;
    int s = 0;
    while (off >= t.seg[s].n) { off -= t.seg[s].n; s++; }
    const PSeg& sg = t.seg[s];
    if (sg.type == 0) {
      float v = 0.f;
      if (!sg.zero)
        v = fp32 ? ((const float*)sg.src)[off]
                 : __bfloat162float(((const __hip_bfloat16*)sg.src)[off]);
      if (sg.dst) sg.dst[off] = v;
      if (sg.hi) {
        __hip_bfloat16 h = __float2bfloat16(v);
        __hip_bfloat16 l = __float2bfloat16(v - __bfloat162float(h));
        sg.hi[off] = h;
        sg.lo[off] = l;
        if (sg.hi2) {  // x -> em cols 0:512 (row width 512 -> 768)
          long d2 = (off >> 9) * DD + (off & 511);
          sg.hi2[d2] = h;
          sg.lo2[d2] = l;
        }
      }
    } else {
      int r = (int)(off % sg.R), c = (int)(off / sg.R);
      float v = fp32 ? ((const float*)sg.src)[(long)r * sg.C + c]
                     : __bfloat162float(((const __hip_bfloat16*)sg.src)[(long)r * sg.C + c]);
      __hip_bfloat16 h = __float2bfloat16(v);
      long d = (long)c * sg.ld + sg.off + r;
      sg.hi[d] = h;
      sg.lo[d] = __float2bfloat16(v - __bfloat162float(h));
    }
  }
}

// ---- wt_nat[r][f][h] = sum_b comp[r,b]*basis[b][f][h] ------------------------
__global__ __launch_bounds__(256) void wt_gemm(
    const float* __restrict__ basis, const float* __restrict__ comp,
    float* __restrict__ wt_nat) {
  __shared__ float cs[RR * NBASE];
  int tid = threadIdx.x;
  for (int i = tid; i < RR * NBASE; i += 256) cs[i] = comp[i];
  __syncthreads();
  long col = (long)blockIdx.x * 256 + tid;
  float acc[RR] = {};
  for (int b = 0; b < NBASE; ++b) {
    float v = basis[(long)b * 131072 + col];
#pragma unroll
    for (int r = 0; r < RR; ++r) acc[r] += cs[r * NBASE + b] * v;
  }
#pragma unroll
  for (int r = 0; r < RR; ++r) wt_nat[(long)r * 131072 + col] = acc[r];
}

// ---- wt_nat [16][512][256] (r,f,h) -> wtc[(r*256+h)][512] hi/lo --------------
__global__ __launch_bounds__(256) void wt_transpose(
    const float* __restrict__ wt_nat,
    __hip_bfloat16* __restrict__ hi, __hip_bfloat16* __restrict__ lo) {
  __shared__ float t[32][33];
  const int r = blockIdx.z;
  const int f0 = blockIdx.y * 32, h0 = blockIdx.x * 32;
  const int c = threadIdx.x & 31, rw = threadIdx.x >> 5;
  const float* src = wt_nat + ((long)r * 512 + f0) * 256 + h0;
#pragma unroll
  for (int i = 0; i < 4; ++i)
    t[rw + i * 8][c] = src[(long)(rw + i * 8) * 256 + c];
  __syncthreads();
#pragma unroll
  for (int i = 0; i < 4; ++i) {
    int hh = rw + i * 8;
    float v = t[c][hh];
    long orow = (long)(r * 256 + h0 + hh) * 512 + f0 + c;
    __hip_bfloat16 hv = __float2bfloat16(v);
    hi[orow] = hv;
    lo[orow] = __float2bfloat16(v - __bfloat162float(hv));
  }
}

// ---------------- fused dual-precision MFMA GEMM ------------------------------
// One K-pass: acc += Ahi@Bhi + Ahi@Blo (+ Alo@Bhi). 128x128 tile, BK=32,
// 4 waves, 16x16x32 bf16 MFMA, global_load_lds w=16.
// __launch_bounds__(256,3): keep 3 blocks/CU.
__device__ __forceinline__ void gload_lds16(const void* g, void* l) {
  __builtin_amdgcn_global_load_lds(
      (const __attribute__((address_space(1))) unsigned int*)g,
      (__attribute__((address_space(3))) unsigned int*)l, 16, 0, 0);
}

__global__ __launch_bounds__(256, 3) void mfma_dual(
    const __hip_bfloat16* __restrict__ A, const __hip_bfloat16* __restrict__ Alo,
    const __hip_bfloat16* __restrict__ Bt, const __hip_bfloat16* __restrict__ Btlo,
    const float* __restrict__ bias, float* __restrict__ C, float* __restrict__ Ct,
    __hip_bfloat16* __restrict__ Chi, __hip_bfloat16* __restrict__ Clo,
    __hip_bfloat16* __restrict__ Chi2, __hip_bfloat16* __restrict__ Clo2,
    int K, int ldc, long sA, long sB, long sC, int flags) {
  __shared__ __hip_bfloat16 Ah[128 * 32];
  __shared__ __hip_bfloat16 Bh[128 * 32];
  __shared__ __hip_bfloat16 Al[128 * 32];
  __shared__ __hip_bfloat16 Bl[128 * 32];
  const int tid = threadIdx.x;
  const int w = tid >> 6, lane = tid & 63;
  const long z = blockIdx.z;
  const long row0 = (long)blockIdx.y * 128, col0 = (long)blockIdx.x * 128;
  const int wm = w & 1, wn = w >> 1;
  const int srow0 = (w * 128 + lane) >> 2;
  const int srow1 = (w * 128 + 64 + lane) >> 2;
  const int kch = (lane & 3) * 8;
  const int fr = lane & 15, q = lane >> 4;
  const bool hasAlo = (Alo != nullptr);
  const __hip_bfloat16* Az = A + z * sA;
  const __hip_bfloat16* Alz = hasAlo ? (Alo + z * sA) : nullptr;
  const __hip_bfloat16* Bz = Bt + z * sB;
  const __hip_bfloat16* Blz = Btlo + z * sB;
  const long aoff0 = (row0 + srow0) * K + kch, aoff1 = (row0 + srow1) * K + kch;
  const long boff0 = (col0 + srow0) * K + kch, boff1 = (col0 + srow1) * K + kch;
  f32x4 acc[4][4] = {};
  for (int k0 = 0; k0 < K; k0 += 32) {
    gload_lds16(Az + aoff0 + k0, Ah + w * 1024);
    gload_lds16(Az + aoff1 + k0, Ah + w * 1024 + 512);
    gload_lds16(Bz + boff0 + k0, Bh + w * 1024);
    gload_lds16(Bz + boff1 + k0, Bh + w * 1024 + 512);
    gload_lds16(Blz + boff0 + k0, Bl + w * 1024);
    gload_lds16(Blz + boff1 + k0, Bl + w * 1024 + 512);
    if (hasAlo) {
      gload_lds16(Alz + aoff0 + k0, Al + w * 1024);
      gload_lds16(Alz + aoff1 + k0, Al + w * 1024 + 512);
    }
    __syncthreads();
    bf16x8 ah[4], bh[4], bl[4];
#pragma unroll
    for (int i = 0; i < 4; ++i) {
      ah[i] = *(const bf16x8*)&Ah[(wm * 64 + i * 16 + fr) * 32 + q * 8];
      bh[i] = *(const bf16x8*)&Bh[(wn * 64 + i * 16 + fr) * 32 + q * 8];
      bl[i] = *(const bf16x8*)&Bl[(wn * 64 + i * 16 + fr) * 32 + q * 8];
    }
#pragma unroll
    for (int i = 0; i < 4; ++i)
#pragma unroll
      for (int j = 0; j < 4; ++j) {
        acc[i][j] = __builtin_amdgcn_mfma_f32_16x16x32_bf16(ah[i], bh[j], acc[i][j], 0, 0, 0);
        acc[i][j] = __builtin_amdgcn_mfma_f32_16x16x32_bf16(ah[i], bl[j], acc[i][j], 0, 0, 0);
      }
    if (hasAlo) {
      bf16x8 al[4];
#pragma unroll
      for (int i = 0; i < 4; ++i)
        al[i] = *(const bf16x8*)&Al[(wm * 64 + i * 16 + fr) * 32 + q * 8];
#pragma unroll
      for (int i = 0; i < 4; ++i)
#pragma unroll
        for (int j = 0; j < 4; ++j)
          acc[i][j] = __builtin_amdgcn_mfma_f32_16x16x32_bf16(al[i], bh[j], acc[i][j], 0, 0, 0);
    }
    __syncthreads();
  }
  const int cr = (lane >> 4) * 4, cc = lane & 15;
  float* Cz = C ? (C + z * sC) : nullptr;
  __hip_bfloat16* Chz = Chi ? (Chi + z * sC) : nullptr;
  __hip_bfloat16* Clz = Clo ? (Clo + z * sC) : nullptr;
#pragma unroll
  for (int i = 0; i < 4; ++i) {
    long rbase = row0 + wm * 64 + i * 16 + cr;
#pragma unroll
    for (int j = 0; j < 4; ++j) {
      long col = col0 + wn * 64 + j * 16 + cc;
      float bv = (flags & FLAG_BIAS) ? bias[col] : 0.f;
#pragma unroll
      for (int r = 0; r < 4; ++r) {
        float v = acc[i][j][r] + bv;
        if (flags & FLAG_RELU) v = fmaxf(v, 0.f);
        if (flags & FLAG_TANH) v = tanhf(v);
        long row = rbase + r;
        if ((flags & FLAG_TAIL2) && col >= 768) {
          // per-batch transposed split: emwT[b][col-768][row&255]
          long off2 = (row >> 8) * 65536 + (col - 768) * 256 + (row & 255);
          __hip_bfloat16 hv = __float2bfloat16(v);
          Chi2[off2] = hv;
          Clo2[off2] = __float2bfloat16(v - __bfloat162float(hv));
        } else if (flags & FLAG_SPLITOUT) {
          long off = row * ldc + col;
          __hip_bfloat16 hv = __float2bfloat16(v);
          Chz[off] = hv;
          Clz[off] = __float2bfloat16(v - __bfloat162float(hv));
        } else if ((flags & FLAG_TAILOUT) && col >= 4096) {
          Ct[row * 256 + (col - 4096)] = v;
        } else {
          Cz[row * ldc + col] = v;
        }
      }
    }
  }
}

// ---------------- edge kernels: CSR build + gathers ----------------------------
__global__ __launch_bounds__(256) void count_edges(
    const int* __restrict__ ei, const int* __restrict__ et, float* __restrict__ cnt) {
  int e = blockIdx.x * 256 + threadIdx.x;
  if (e < EE) atomicAdd(&cnt[ei[EE + e] * RR + et[e]], 1.0f);
}

__global__ __launch_bounds__(256) void scan_rowptr(
    const float* __restrict__ cntf, int* __restrict__ rowptr, int* __restrict__ fill) {
  __shared__ int part[256];
  int tid = threadIdx.x;
  int base = tid * 32;
  int local[32];
  int s = 0;
  for (int i = 0; i < 32; ++i) {
    local[i] = s;
    const float* c = &cntf[(base + i) * RR];
    int d = 0;
#pragma unroll
    for (int r = 0; r < RR; ++r) d += (int)c[r];
    s += d;
  }
  part[tid] = s;
  __syncthreads();
  for (int off = 1; off < 256; off <<= 1) {
    int v = (tid >= off) ? part[tid - off] : 0;
    __syncthreads();
    part[tid] += v;
    __syncthreads();
  }
  int prev = (tid == 0) ? 0 : part[tid - 1];
  for (int i = 0; i < 32; ++i) rowptr[base + i] = prev + local[i];
  if (tid == 255) rowptr[8192] = part[255];
  for (int i = tid; i < 8192; i += 256) fill[i] = 0;
}

__global__ __launch_bounds__(256) void edge_fill(
    const int* __restrict__ ei, const int* __restrict__ et,
    const int* __restrict__ rowptr, int* __restrict__ fill, int* __restrict__ eidx) {
  int e = blockIdx.x * 256 + threadIdx.x;
  if (e < EE) {
    int dst = ei[EE + e];
    int pos = rowptr[dst] + atomicAdd(&fill[dst], 1);
    eidx[pos] = ei[e] | (et[e] << 16);
  }
}

// out1 += mean-agg; also emit split into a2o1 cols 256:512 (A of out2 GEMM)
__global__ __launch_bounds__(256) void rgcn_gather(
    const int* __restrict__ rowptr, const int* __restrict__ eidx,
    const float* __restrict__ cntf, const float* __restrict__ xw,
    float* __restrict__ out1, __hip_bfloat16* __restrict__ a2o1_hi,
    __hip_bfloat16* __restrict__ a2o1_lo) {
  const int dst = blockIdx.x;
  const int h = threadIdx.x;
  __shared__ float inv[RR];
  __shared__ int se[256];
  if (h < RR) inv[h] = 1.0f / fmaxf(cntf[dst * RR + h], 1.0f);
  const int beg = rowptr[dst], end = rowptr[dst + 1];
  float a0 = 0.f, a1 = 0.f, a2 = 0.f, a3 = 0.f;
  for (int c0 = beg; c0 < end; c0 += 256) {
    int n = min(256, end - c0);
    __syncthreads();
    if (h < n) se[h] = eidx[c0 + h];
    __syncthreads();
    int i = 0;
    for (; i + 4 <= n; i += 4) {
      int p0 = se[i], p1 = se[i + 1], p2 = se[i + 2], p3 = se[i + 3];
      float v0 = xw[((long)(p0 & 0xFFFF) << 12) + ((p0 >> 16) << 8) + h];
      float v1 = xw[((long)(p1 & 0xFFFF) << 12) + ((p1 >> 16) << 8) + h];
      float v2 = xw[((long)(p2 & 0xFFFF) << 12) + ((p2 >> 16) << 8) + h];
      float v3 = xw[((long)(p3 & 0xFFFF) << 12) + ((p3 >> 16) << 8) + h];
      a0 += v0 * inv[p0 >> 16];
      a1 += v1 * inv[p1 >> 16];
      a2 += v2 * inv[p2 >> 16];
      a3 += v3 * inv[p3 >> 16];
    }
    for (; i < n; ++i) {
      int pk = se[i];
      a0 += xw[((long)(pk & 0xFFFF) << 12) + ((pk >> 16) << 8) + h] * inv[pk >> 16];
    }
  }
  float tot = out1[((long)dst << 8) + h] + ((a0 + a1) + (a2 + a3));
  out1[((long)dst << 8) + h] = tot;
  __hip_bfloat16 hv = __float2bfloat16(tot);
  long d = (long)dst * 512 + 256 + h;
  a2o1_hi[d] = hv;
  a2o1_lo[d] = __float2bfloat16(tot - __bfloat162float(hv));
}

// a2o1 cols 0:256 = sum_{src->dst} out1[src] (split)
__global__ __launch_bounds__(256) void graphconv_gather(
    const int* __restrict__ rowptr, const int* __restrict__ eidx,
    const float* __restrict__ out1, __hip_bfloat16* __restrict__ a2o1_hi,
    __hip_bfloat16* __restrict__ a2o1_lo) {
  const int dst = blockIdx.x;
  const int h = threadIdx.x;
  __shared__ int se[256];
  const int beg = rowptr[dst], end = rowptr[dst + 1];
  float a0 = 0.f, a1 = 0.f, a2 = 0.f, a3 = 0.f;
  for (int c0 = beg; c0 < end; c0 += 256) {
    int n = min(256, end - c0);
    __syncthreads();
    if (h < n) se[h] = eidx[c0 + h];
    __syncthreads();
    int i = 0;
    for (; i + 4 <= n; i += 4) {
      a0 += out1[((long)(se[i] & 0xFFFF) << 8) + h];
      a1 += out1[((long)(se[i + 1] & 0xFFFF) << 8) + h];
      a2 += out1[((long)(se[i + 2] & 0xFFFF) << 8) + h];
      a3 += out1[((long)(se[i + 3] & 0xFFFF) << 8) + h];
    }
    for (; i < n; ++i) a0 += out1[((long)(se[i] & 0xFFFF) << 8) + h];
  }
  float acc = (a0 + a1) + (a2 + a3);
  __hip_bfloat16 hv = __float2bfloat16(acc);
  long d = (long)dst * 512 + h;
  a2o1_hi[d] = hv;
  a2o1_lo[d] = __float2bfloat16(acc - __bfloat162float(hv));
}

// ---------------- softmax over last dim (256), bf16 weights out ---------------
__global__ __launch_bounds__(256) void softmax256(const float* __restrict__ S,
                                                  __hip_bfloat16* __restrict__ Ab) {
  __shared__ float red[256];
  long row = blockIdx.x;
  const float* p = S + row * 256;
  int t = threadIdx.x;
  float v = p[t];
  red[t] = v;
  __syncthreads();
  for (int s = 128; s > 0; s >>= 1) {
    if (t < s) red[t] = fmaxf(red[t], red[t + s]);
    __syncthreads();
  }
  float m = red[0];
  __syncthreads();
  float e = __expf(v - m);
  red[t] = e;
  __syncthreads();
  for (int s = 128; s > 0; s >>= 1) {
    if (t < s) red[t] += red[t + s];
    __syncthreads();
  }
  Ab[row * 256 + t] = __float2bfloat16(e / red[0]);
}

// ---------------- logits + log_softmax over batch axis (faithful dim=1) -------
__global__ __launch_bounds__(256) void logits_lsm(
    const float* __restrict__ hidden, const float* __restrict__ w_fc,
    const float* __restrict__ b_fc, void* __restrict__ out_v,
    const int* __restrict__ flag) {
  __shared__ float wf[256 * 7];
  __shared__ float lg[224];
  __shared__ float corr[7];
  int t = blockIdx.x;
  int tid = threadIdx.x;
  for (int i = tid; i < 256 * 7; i += 256) wf[i] = w_fc[i];
  __syncthreads();
  if (tid < 224) {
    int b = tid / 7, c = tid % 7;
    const float* hr = hidden + ((long)((b << 8) + t) << 8);
    float s = b_fc[c];
    for (int k = 0; k < 256; ++k) s += hr[k] * wf[k * 7 + c];
    lg[tid] = s;
  }
  __syncthreads();
  if (tid < 7) {
    float m = -1e30f;
    for (int b = 0; b < BB; ++b) m = fmaxf(m, lg[b * 7 + tid]);
    float sum = 0.f;
    for (int b = 0; b < BB; ++b) sum += __expf(lg[b * 7 + tid] - m);
    corr[tid] = m + logf(sum);
  }
  __syncthreads();
  if (tid < 224) {
    float v = lg[tid] - corr[tid % 7];
    if (flag[0]) ((float*)out_v)[t * 224 + tid] = v;
    else ((__hip_bfloat16*)out_v)[t * 224 + tid] = __float2bfloat16(v);
  }
}

extern "C" void kernel_launch(void* const* d_in, const int* in_sizes, int n_in,
                              void* d_out, int out_size, void* d_ws, size_t ws_size,
                              hipStream_t stream) {
  const int* ei = (const int*)d_in[1];
  const int* et = (const int*)d_in[3];

  float* ws = (float*)d_ws;
  int* flag = (int*)d_ws;
  float* p = ws + 16;
  auto alloc = [&](long nf) { float* r = p; p += nf; return r; };
  float* w_fc_f = alloc(1792);
  float* b_rel_f = alloc(256);
  float* biasx = alloc(4352);                                    // [0..4095]=0, tail=bias1
  float* battx = alloc(1024);                                    // [0..767]=b_att, rest 0
  float* b_lin_f = alloc(256);
  float* b_fc_f = alloc(16);
  __hip_bfloat16* x_hi = (__hip_bfloat16*)alloc(2097152);        // [8192][512]
  __hip_bfloat16* x_lo = (__hip_bfloat16*)alloc(2097152);
  __hip_bfloat16* wae_hi = (__hip_bfloat16*)alloc(393216);       // [1024][768] = [w_att|w_lin]^T
  __hip_bfloat16* wae_lo = (__hip_bfloat16*)alloc(393216);
  __hip_bfloat16* wrr_hi = (__hip_bfloat16*)alloc(65536);        // [256][512] = [w_rel;w_root]^T
  __hip_bfloat16* wrr_lo = (__hip_bfloat16*)alloc(65536);
  __hip_bfloat16* wtc_hi = (__hip_bfloat16*)alloc(1114112);      // [4352][512]
  __hip_bfloat16* wtc_lo = (__hip_bfloat16*)alloc(1114112);
  float* basis_f = alloc(3932160);
  float* comp_f = alloc(512);
  float* xw = alloc(33554432);   // fp32 [8192][4096]; overlays below
  float* cnt = alloc(131072);
  float* out1 = alloc(2097152);
  __hip_bfloat16* a2o1_hi = (__hip_bfloat16*)alloc(2097152);     // [8192][512]
  __hip_bfloat16* a2o1_lo = (__hip_bfloat16*)alloc(2097152);
  float* hidden = alloc(2097152);
  int* rowptr = (int*)alloc(8208);
  int* fillc = (int*)alloc(8192);
  int* eidx = (int*)alloc(262144);
  // wt_nat overlays head of xw (consumed by wt_transpose before xw is written)
  float* wt_nat = xw;                                            // [16][512][256]
  // phase B overlays the (consumed) xw region
  float* em = xw;
  __hip_bfloat16* emwT_hi = (__hip_bfloat16*)(em + 2097152);     // [32][256][256]
  __hip_bfloat16* emwT_lo = (__hip_bfloat16*)(em + 3145728);
  __hip_bfloat16* em_hi = (__hip_bfloat16*)(em + 6291456);       // [8192][768]
  __hip_bfloat16* em_lo = (__hip_bfloat16*)(em + 9437184);
  __hip_bfloat16* X_hi = (__hip_bfloat16*)(em + 12582912);
  __hip_bfloat16* X_lo = (__hip_bfloat16*)(em + 15728640);
  float* scores = em + 18874368;                                 // 2,097,152 f
  __hip_bfloat16* a_b16 = (__hip_bfloat16*)(em + 20971520);      // 1,048,576 f

  // 0. dtype detect + one unified prep launch
  detect_dtype<<<1, 256, 0, stream>>>((const unsigned short*)d_in[0], flag);
  PTable T{};
  long tot = 0;
  int ns = 0;
  auto segL = [&](const void* s, float* d, __hip_bfloat16* hi, __hip_bfloat16* lo,
                  __hip_bfloat16* hi2, __hip_bfloat16* lo2, long n, int z) {
    T.seg[ns] = PSeg{s, d, hi, lo, hi2, lo2, n, 0, 0, 0, 0, 0, z};
    ns++; tot += n;
  };
  auto segT = [&](const void* s, __hip_bfloat16* hi, __hip_bfloat16* lo,
                  int R, int C, int ld, int off) {
    T.seg[ns] = PSeg{s, nullptr, hi, lo, nullptr, nullptr, (long)R * C, R, C, ld, off, 1, 0};
    ns++; tot += (long)R * C;
  };
  // NOTE: em_hi/em_lo writes here land in the xw-overlay region; they are
  // overwritten by wt_nat/xw and rewritten?  NO — em overlays xw which is
  // written AFTER prep.  So x->em copy must happen after xw is consumed.
  segL(d_in[0], nullptr, x_hi, x_lo, nullptr, nullptr, NN * FF, 0);
  segL(d_in[8], basis_f, nullptr, nullptr, nullptr, nullptr, NBASE * FF * HH, 0);
  segL(d_in[9], comp_f, nullptr, nullptr, nullptr, nullptr, RR * NBASE, 0);
  segL(d_in[13], b_rel_f, nullptr, nullptr, nullptr, nullptr, HH, 0);
  segL(d_in[16], battx, nullptr, nullptr, nullptr, nullptr, DD, 0);
  segL(nullptr, battx + DD, nullptr, nullptr, nullptr, nullptr, 256, 1);
  segL(d_in[18], b_lin_f, nullptr, nullptr, nullptr, nullptr, HH, 0);
  segL(d_in[19], w_fc_f, nullptr, nullptr, nullptr, nullptr, HH * CC, 0);
  segL(d_in[20], b_fc_f, nullptr, nullptr, nullptr, nullptr, CC, 0);
  segL(nullptr, biasx, nullptr, nullptr, nullptr, nullptr, 4096, 1);
  segL(d_in[11], biasx + 4096, nullptr, nullptr, nullptr, nullptr, HH, 0);
  segT(d_in[15], wae_hi, wae_lo, DD, DD, DD, 0);                 // w_att^T -> rows 0:768
  segT(d_in[17], wae_hi + 768 * 768, wae_lo + 768 * 768, DD, HH, DD, 0);  // w_lin^T -> rows 768:1024
  segT(d_in[10], wtc_hi + 4096 * 512, wtc_lo + 4096 * 512, FF, HH, FF, 0);  // root1^T
  segT(d_in[12], wrr_hi, wrr_lo, HH, HH, 512, 0);                // w_rel^T
  segT(d_in[14], wrr_hi, wrr_lo, HH, HH, 512, 256);              // w_root^T
  T.count = ns;
  T.total = tot;
  prep_all<<<4096, 256, 0, stream>>>(T, flag);

  // 1. Wt: coalesced GEMM into natural layout, then LDS-tiled transpose + split
  wt_gemm<<<131072 / 256, 256, 0, stream>>>(basis_f, comp_f, wt_nat);
  wt_transpose<<<dim3(8, 16, 16), 256, 0, stream>>>(wt_nat, wtc_hi, wtc_lo);
  // 2. merged xw|out1 = x @ [W | root1] + [0 | bias1]  (cols>=4096 -> out1)
  mfma_dual<<<dim3(34, 64, 1), 256, 0, stream>>>(
      x_hi, x_lo, wtc_hi, wtc_lo, biasx, xw, out1, nullptr, nullptr, nullptr, nullptr,
      FF, 4096, 0, 0, 0, FLAG_BIAS | FLAG_TAILOUT);
  // 3. CSR build
  hipMemsetAsync(cnt, 0, 131072 * sizeof(float), stream);
  count_edges<<<EE / 256, 256, 0, stream>>>(ei, et, cnt);
  scan_rowptr<<<1, 256, 0, stream>>>(cnt, rowptr, fillc);
  edge_fill<<<EE / 256, 256, 0, stream>>>(ei, et, rowptr, fillc, eidx);
  // 4/5. aggregations (gather); emit [agg2|out1] hi/lo as out2-GEMM A operand
  rgcn_gather<<<NN, 256, 0, stream>>>(rowptr, eidx, cnt, xw, out1, a2o1_hi, a2o1_lo);
  graphconv_gather<<<NN, 256, 0, stream>>>(rowptr, eidx, out1, a2o1_hi, a2o1_lo);
  // 6. em cols 0:512 = x (split, from x_hi/x_lo after xw is dead)
  {
    PTable T2{};
    T2.seg[0] = PSeg{nullptr, nullptr, nullptr, nullptr, nullptr, nullptr,
                     (long)NN * FF, 0, 0, 0, 0, 2, 0};
    // reuse prep_all? simpler: dedicated copy below
  }
  // dedicated copy kernel (reuse prep_all linear path with bf16 src = x_hi? no:
  // x data identical; use small copy via prep-style lambda kernel):
  // (implemented as a simple kernel launch)
  {
    struct { const __hip_bfloat16 *xh, *xl; __hip_bfloat16 *eh, *el; } args{x_hi, x_lo, em_hi, em_lo};
    // inline lambda-kernel not available; use loop below
  }
  // simple copy kernel:
  extern __global__ void copy_xsplit_k(const __hip_bfloat16*, const __hip_bfloat16*,
                                       __hip_bfloat16*, __hip_bfloat16*);
  copy_xsplit_k<<<(NN * FF) / 256, 256, 0, stream>>>(x_hi, x_lo, em_hi, em_lo);
  // 6b. out2 -> em cols 512:768 via split-MFMA
  mfma_dual<<<dim3(2, 64, 1), 256, 0, stream>>>(
      a2o1_hi, a2o1_lo, wrr_hi, wrr_lo, b_rel_f, nullptr, nullptr,
      em_hi + 512, em_lo + 512, nullptr, nullptr, 512, DD, 0, 0, 0,
      FLAG_BIAS | FLAG_SPLITOUT);
  // 7. [X | emwT] = em @ [w_att | w_lin] (+b_att|0); cols>=768 -> transposed split
  mfma_dual<<<dim3(8, 64, 1), 256, 0, stream>>>(
      em_hi, em_lo, wae_hi, wae_lo, battx, nullptr, nullptr, X_hi, X_lo,
      emwT_hi, emwT_lo, DD, DD, 0, 0, 0, FLAG_BIAS | FLAG_SPLITOUT | FLAG_TAIL2);
  // 8. scores = tanh(X_b . em_b^T) (batched, fp32 out)
  mfma_dual<<<dim3(2, 2, BB), 256, 0, stream>>>(
      X_hi, X_lo, em_hi, em_lo, nullptr, scores, nullptr, nullptr, nullptr,
      nullptr, nullptr, DD, LL, (long)LL * DD, (long)LL * DD, (long)LL * LL, FLAG_TANH);
  // 9. softmax over s -> bf16 attention weights
  softmax256<<<BB * LL, 256, 0, stream>>>(scores, a_b16);
  // 10. hidden = relu(a @ emwT + b_lin)
  mfma_dual<<<dim3(2, 2, BB), 256, 0, stream>>>(
      a_b16, nullptr, emwT_hi, emwT_lo, b_lin_f, hidden, nullptr, nullptr, nullptr,
      nullptr, nullptr, LL, HH, (long)LL * LL, (long)LL * HH, (long)LL * HH,
      FLAG_BIAS | FLAG_RELU);
  // 11. logits + log_softmax over batch axis
  logits_lsm<<<LL, 256, 0, stream>>>(hidden, w_fc_f, b_fc_f, d_out, flag);
}

// copy x_hi/x_lo [8192][512] into em_hi/lo [8192][768] cols 0:512
__global__ __launch_bounds__(256) void copy_xsplit_k(
    const __hip_bfloat16* __restrict__ xh, const __hip_bfloat16* __restrict__ xl,
    __hip_bfloat16* __restrict__ eh, __hip_bfloat16* __restrict__ el) {
  int idx = blockIdx.x * 256 + threadIdx.x;  // 8192*512
  int n = idx >> 9, f = idx & 511;
  long d = (long)n * DD + f;
  eh[d] = xh[idx];
  el[d] = xl[idx];
}